// Round 2
// baseline (11657.434 us; speedup 1.0000x reference)
//
#include <hip/hip_runtime.h>

#define DMODEL 1024
#define DINNER 2048
#define NSTATE 4
#define DTRANK 64
#define XDBLN  72
#define SEQL   4096
#define NB     2
#define NTOK   (NB * SEQL)

typedef unsigned short ushort_t;

__device__ __forceinline__ float bf2f(ushort_t h) {
    return __uint_as_float(((unsigned int)h) << 16);
}
__device__ __forceinline__ ushort_t f2bf(float f) {
    unsigned int u = __float_as_uint(f);
    u += 0x7fffu + ((u >> 16) & 1u);   // round-to-nearest-even
    return (ushort_t)(u >> 16);
}

// ---------------- RMSNorm: one block per token ----------------
template <bool OUT_BF16>
__global__ __launch_bounds__(256) void rmsnorm_kernel(
    const float* __restrict__ in, const float* __restrict__ w,
    void* __restrict__ outv)
{
    const int t = blockIdx.x;
    const int tid = threadIdx.x;
    const float4 v = reinterpret_cast<const float4*>(in + (size_t)t * DMODEL)[tid];
    float ss = v.x * v.x + v.y * v.y + v.z * v.z + v.w * v.w;
#pragma unroll
    for (int o = 32; o > 0; o >>= 1) ss += __shfl_xor(ss, o, 64);
    __shared__ float red[4];
    if ((tid & 63) == 0) red[tid >> 6] = ss;
    __syncthreads();
    const float total = red[0] + red[1] + red[2] + red[3];
    const float scale = rsqrtf(total * (1.0f / DMODEL) + 1e-5f);
    const float4 wv = reinterpret_cast<const float4*>(w)[tid];
    const float o0 = v.x * scale * wv.x;
    const float o1 = v.y * scale * wv.y;
    const float o2 = v.z * scale * wv.z;
    const float o3 = v.w * scale * wv.w;
    if (OUT_BF16) {
        ushort4 o;
        o.x = f2bf(o0); o.y = f2bf(o1); o.z = f2bf(o2); o.w = f2bf(o3);
        reinterpret_cast<ushort4*>((ushort_t*)outv + (size_t)t * DMODEL)[tid] = o;
    } else {
        float4 o; o.x = o0; o.y = o1; o.z = o2; o.w = o3;
        reinterpret_cast<float4*>((float*)outv + (size_t)t * DMODEL)[tid] = o;
    }
}

// ---------------- GEMM: C = A(bf16) @ B(f32) (+bias) (softplus?) (+resid f32) ----------------
#define TM 128
#define TN 128
#define TK 16

template <bool OUT_BF16>
__global__ __launch_bounds__(256) void gemm_abf16(
    const ushort_t* __restrict__ A, const float* __restrict__ B,
    void* __restrict__ Cv, const float* __restrict__ bias,
    const float* __restrict__ resid,
    int M, int N, int K, int lda, int ldb, int ldc, int act)
{
    __shared__ float As[TK][TM];  // k-major (transposed)
    __shared__ float Bs[TK][TN];
    const int tid = threadIdx.x;
    const int row0 = blockIdx.y * TM;
    const int col0 = blockIdx.x * TN;
    const int tx = tid & 15;
    const int ty = tid >> 4;
    float acc[8][8];
#pragma unroll
    for (int i = 0; i < 8; ++i)
#pragma unroll
        for (int j = 0; j < 8; ++j) acc[i][j] = 0.0f;

    for (int k0 = 0; k0 < K; k0 += TK) {
        // A tile: 128 rows x 16 cols of bf16. Thread: 8 bf16 (one uint4).
        {
            const int row = tid >> 1;
            const int cg = (tid & 1) * 8;
            const uint4 raw = *reinterpret_cast<const uint4*>(
                &A[(size_t)(row0 + row) * lda + k0 + cg]);
            As[cg + 0][row] = __uint_as_float(raw.x << 16);
            As[cg + 1][row] = __uint_as_float(raw.x & 0xffff0000u);
            As[cg + 2][row] = __uint_as_float(raw.y << 16);
            As[cg + 3][row] = __uint_as_float(raw.y & 0xffff0000u);
            As[cg + 4][row] = __uint_as_float(raw.z << 16);
            As[cg + 5][row] = __uint_as_float(raw.z & 0xffff0000u);
            As[cg + 6][row] = __uint_as_float(raw.w << 16);
            As[cg + 7][row] = __uint_as_float(raw.w & 0xffff0000u);
        }
        // B tile: 16 rows x 128 cols of f32. Thread: 8 floats (two float4).
        {
            const int brow = tid >> 4;
            const int bcol = (tid & 15) * 8;
            float4 b0, b1;
            if (col0 + bcol < N) {
                b0 = *reinterpret_cast<const float4*>(
                    &B[(size_t)(k0 + brow) * ldb + col0 + bcol]);
                b1 = *reinterpret_cast<const float4*>(
                    &B[(size_t)(k0 + brow) * ldb + col0 + bcol + 4]);
            } else {
                b0 = make_float4(0.f, 0.f, 0.f, 0.f);
                b1 = b0;
            }
            *reinterpret_cast<float4*>(&Bs[brow][bcol]) = b0;
            *reinterpret_cast<float4*>(&Bs[brow][bcol + 4]) = b1;
        }
        __syncthreads();
#pragma unroll
        for (int k = 0; k < TK; ++k) {
            float a[8], b[8];
            *reinterpret_cast<float4*>(&a[0]) = *reinterpret_cast<const float4*>(&As[k][ty * 8]);
            *reinterpret_cast<float4*>(&a[4]) = *reinterpret_cast<const float4*>(&As[k][ty * 8 + 4]);
            *reinterpret_cast<float4*>(&b[0]) = *reinterpret_cast<const float4*>(&Bs[k][tx * 8]);
            *reinterpret_cast<float4*>(&b[4]) = *reinterpret_cast<const float4*>(&Bs[k][tx * 8 + 4]);
#pragma unroll
            for (int i = 0; i < 8; ++i)
#pragma unroll
                for (int j = 0; j < 8; ++j) acc[i][j] += a[i] * b[j];
        }
        __syncthreads();
    }

#pragma unroll
    for (int i = 0; i < 8; ++i) {
        const int r = row0 + ty * 8 + i;
#pragma unroll
        for (int jj = 0; jj < 2; ++jj) {
            const int c = col0 + tx * 8 + jj * 4;
            if (c >= N) continue;
            float v0 = acc[i][jj * 4 + 0];
            float v1 = acc[i][jj * 4 + 1];
            float v2 = acc[i][jj * 4 + 2];
            float v3 = acc[i][jj * 4 + 3];
            if (bias) {
                v0 += bias[c + 0]; v1 += bias[c + 1];
                v2 += bias[c + 2]; v3 += bias[c + 3];
            }
            if (act == 1) {  // softplus
                v0 = fmaxf(v0, 0.f) + log1pf(expf(-fabsf(v0)));
                v1 = fmaxf(v1, 0.f) + log1pf(expf(-fabsf(v1)));
                v2 = fmaxf(v2, 0.f) + log1pf(expf(-fabsf(v2)));
                v3 = fmaxf(v3, 0.f) + log1pf(expf(-fabsf(v3)));
            }
            if (resid) {
                const float4 rv = *reinterpret_cast<const float4*>(
                    &resid[(size_t)r * ldc + c]);
                v0 += rv.x; v1 += rv.y; v2 += rv.z; v3 += rv.w;
            }
            if (OUT_BF16) {
                ushort4 o;
                o.x = f2bf(v0); o.y = f2bf(v1); o.z = f2bf(v2); o.w = f2bf(v3);
                *reinterpret_cast<ushort4*>(&((ushort_t*)Cv)[(size_t)r * ldc + c]) = o;
            } else {
                float4 o; o.x = v0; o.y = v1; o.z = v2; o.w = v3;
                *reinterpret_cast<float4*>(&((float*)Cv)[(size_t)r * ldc + c]) = o;
            }
        }
    }
}

// ---------------- Causal depthwise conv (K=4) + bias + SiLU (bf16 in/out) ----------------
__global__ __launch_bounds__(256) void conv_silu_kernel(
    const ushort_t* __restrict__ xr, const float* __restrict__ w,
    const float* __restrict__ bcv, ushort_t* __restrict__ xi)
{
    const int idx = blockIdx.x * 256 + threadIdx.x;  // B*L*DINNER = 2^24
    const int c = idx & (DINNER - 1);
    const int l = (idx >> 11) & (SEQL - 1);
    const int b = idx >> 23;
    const float w0 = w[c * 4 + 0], w1 = w[c * 4 + 1], w2 = w[c * 4 + 2], w3 = w[c * 4 + 3];
    const size_t base = ((size_t)(b * SEQL + l)) * DINNER + c;
    float s = bcv[c];
    if (l >= 3) s += w0 * bf2f(xr[base - 3 * DINNER]);
    if (l >= 2) s += w1 * bf2f(xr[base - 2 * DINNER]);
    if (l >= 1) s += w2 * bf2f(xr[base - 1 * DINNER]);
    s += w3 * bf2f(xr[base]);
    const float sig = 1.0f / (1.0f + expf(-s));
    xi[base] = f2bf(s * sig);
}

// ---------------- Selective scan, fused D-skip and *silu(res) ----------------
__global__ __launch_bounds__(64) void scan_kernel(
    const ushort_t* __restrict__ delta, const ushort_t* __restrict__ u_in,
    const ushort_t* __restrict__ xdbl, const ushort_t* __restrict__ res_in,
    const float* __restrict__ A_log, const float* __restrict__ D_skip,
    ushort_t* __restrict__ y_out)
{
    const int gtid = blockIdx.x * 64 + threadIdx.x;  // B*DINNER*NSTATE = 16384
    const int n = gtid & 3;
    const int g = gtid >> 2;
    const int d = g & (DINNER - 1);
    const int b = g >> 11;
    const float An = -expf(A_log[d * NSTATE + n]);
    const float Dk = D_skip[d];
    float h = 0.0f;
    size_t idx_du = (size_t)b * SEQL * DINNER + d;
    size_t idx_bc = (size_t)b * SEQL * XDBLN;
    for (int l = 0; l < SEQL; ++l) {
        const float dv = bf2f(delta[idx_du]);
        const float u  = bf2f(u_in[idx_du]);
        const float Bn = bf2f(xdbl[idx_bc + DTRANK + n]);
        const float Cn = bf2f(xdbl[idx_bc + DTRANK + NSTATE + n]);
        const float dA = expf(dv * An);
        h = dA * h + dv * Bn * u;
        float yn = h * Cn;
        yn += __shfl_xor(yn, 1, 4);
        yn += __shfl_xor(yn, 2, 4);
        if (n == 0) {
            const float res = bf2f(res_in[idx_du]);
            const float sil = res / (1.0f + expf(-res));
            y_out[idx_du] = f2bf((yn + u * Dk) * sil);
        }
        idx_du += DINNER;
        idx_bc += XDBLN;
    }
}

// ---------------- Orchestration ----------------
extern "C" void kernel_launch(void* const* d_in, const int* in_sizes, int n_in,
                              void* d_out, int out_size, void* d_ws, size_t ws_size,
                              hipStream_t stream)
{
    const float* x        = (const float*)d_in[0];
    const float* in_proj  = (const float*)d_in[1];
    const float* conv_w   = (const float*)d_in[2];
    const float* conv_b   = (const float*)d_in[3];
    const float* x_proj   = (const float*)d_in[4];
    const float* dt_w     = (const float*)d_in[5];
    const float* dt_b     = (const float*)d_in[6];
    const float* A_log    = (const float*)d_in[7];
    const float* D_skip   = (const float*)d_in[8];
    const float* out_proj = (const float*)d_in[9];
    const float* norm_w   = (const float*)d_in[10];
    const float* norm_f_w = (const float*)d_in[11];
    float* out = (float*)d_out;

    // Workspace layout: 145.1 MB total.
    char* p = (char*)d_ws;
    float*    x_cur = (float*)p;    p += (size_t)NTOK * DMODEL * 4;   // 33.5 MB
    ushort_t* xn    = (ushort_t*)p; p += (size_t)NTOK * DMODEL * 2;   // 16.8 MB
    ushort_t* xraw  = (ushort_t*)p; p += (size_t)NTOK * DINNER * 2;   // 33.5 MB (delta reuses)
    ushort_t* res   = (ushort_t*)p; p += (size_t)NTOK * DINNER * 2;   // 33.5 MB
    ushort_t* xi    = (ushort_t*)p; p += (size_t)NTOK * DINNER * 2;   // 33.5 MB (y in-place)
    ushort_t* xdbl  = (ushort_t*)p; p += (size_t)NTOK * XDBLN * 2;    //  1.2 MB
    const size_t need = (size_t)(p - (char*)d_ws);
    if (ws_size < need) return;  // graceful diagnostic failure instead of page fault
    ushort_t* delta = xraw;      // xraw dead after conv

    for (int i = 0; i < 2; ++i) {
        const float* x_in = (i == 0) ? x : x_cur;
        rmsnorm_kernel<true><<<NTOK, 256, 0, stream>>>(x_in, norm_w + (size_t)i * DMODEL, xn);
        // xraw = xn @ in_proj[:, :2048]; res = xn @ in_proj[:, 2048:]
        {
            dim3 g(DINNER / TN, NTOK / TM);
            gemm_abf16<true><<<g, 256, 0, stream>>>(
                xn, in_proj + (size_t)i * DMODEL * 2 * DINNER, xraw, nullptr, nullptr,
                NTOK, DINNER, DMODEL, DMODEL, 2 * DINNER, DINNER, 0);
            gemm_abf16<true><<<g, 256, 0, stream>>>(
                xn, in_proj + (size_t)i * DMODEL * 2 * DINNER + DINNER, res, nullptr, nullptr,
                NTOK, DINNER, DMODEL, DMODEL, 2 * DINNER, DINNER, 0);
        }
        conv_silu_kernel<<<(NTOK * DINNER) / 256, 256, 0, stream>>>(
            xraw, conv_w + (size_t)i * DINNER * 4, conv_b + (size_t)i * DINNER, xi);
        // xdbl = xi @ x_proj
        {
            dim3 g(1, NTOK / TM);
            gemm_abf16<true><<<g, 256, 0, stream>>>(
                xi, x_proj + (size_t)i * DINNER * XDBLN, xdbl, nullptr, nullptr,
                NTOK, XDBLN, DINNER, DINNER, XDBLN, XDBLN, 0);
        }
        // delta = softplus(xdbl[:, :64] @ dt_w + dt_b)   (delta overwrites xraw)
        {
            dim3 g(DINNER / TN, NTOK / TM);
            gemm_abf16<true><<<g, 256, 0, stream>>>(
                xdbl, dt_w + (size_t)i * DTRANK * DINNER, delta, dt_b + (size_t)i * DINNER, nullptr,
                NTOK, DINNER, DTRANK, XDBLN, DINNER, DINNER, 1);
        }
        // selective scan (y in-place over xi)
        scan_kernel<<<256, 64, 0, stream>>>(
            delta, xi, xdbl, res,
            A_log + (size_t)i * DINNER * NSTATE, D_skip + (size_t)i * DINNER, xi);
        // x_cur = y @ out_proj + x_in
        {
            dim3 g(DMODEL / TN, NTOK / TM);
            gemm_abf16<false><<<g, 256, 0, stream>>>(
                xi, out_proj + (size_t)i * DINNER * DMODEL, x_cur, nullptr, x_in,
                NTOK, DMODEL, DINNER, DINNER, DMODEL, DMODEL, 0);
        }
    }
    rmsnorm_kernel<false><<<NTOK, 256, 0, stream>>>(x_cur, norm_f_w, out);
}

// Round 3
// 6196.861 us; speedup vs baseline: 1.8812x; 1.8812x over previous
//
#include <hip/hip_runtime.h>

#define DMODEL 1024
#define DINNER 2048
#define NSTATE 4
#define DTRANK 64
#define XDBLN  72
#define SEQL   4096
#define NB     2
#define NTOK   (NB * SEQL)
#define CHUNK  64
#define NCHUNK (SEQL / CHUNK)   // 64

typedef unsigned short ushort_t;

__device__ __forceinline__ float bf2f(ushort_t h) {
    return __uint_as_float(((unsigned int)h) << 16);
}
__device__ __forceinline__ ushort_t f2bf(float f) {
    unsigned int u = __float_as_uint(f);
    u += 0x7fffu + ((u >> 16) & 1u);   // round-to-nearest-even
    return (ushort_t)(u >> 16);
}
__device__ __forceinline__ float lo16(unsigned int x) { return __uint_as_float(x << 16); }
__device__ __forceinline__ float hi16(unsigned int x) { return __uint_as_float(x & 0xffff0000u); }

// ---------------- RMSNorm: one block per token ----------------
template <bool OUT_BF16>
__global__ __launch_bounds__(256) void rmsnorm_kernel(
    const float* __restrict__ in, const float* __restrict__ w,
    void* __restrict__ outv)
{
    const int t = blockIdx.x;
    const int tid = threadIdx.x;
    const float4 v = reinterpret_cast<const float4*>(in + (size_t)t * DMODEL)[tid];
    float ss = v.x * v.x + v.y * v.y + v.z * v.z + v.w * v.w;
#pragma unroll
    for (int o = 32; o > 0; o >>= 1) ss += __shfl_xor(ss, o, 64);
    __shared__ float red[4];
    if ((tid & 63) == 0) red[tid >> 6] = ss;
    __syncthreads();
    const float total = red[0] + red[1] + red[2] + red[3];
    const float scale = rsqrtf(total * (1.0f / DMODEL) + 1e-5f);
    const float4 wv = reinterpret_cast<const float4*>(w)[tid];
    const float o0 = v.x * scale * wv.x;
    const float o1 = v.y * scale * wv.y;
    const float o2 = v.z * scale * wv.z;
    const float o3 = v.w * scale * wv.w;
    if (OUT_BF16) {
        ushort4 o;
        o.x = f2bf(o0); o.y = f2bf(o1); o.z = f2bf(o2); o.w = f2bf(o3);
        reinterpret_cast<ushort4*>((ushort_t*)outv + (size_t)t * DMODEL)[tid] = o;
    } else {
        float4 o; o.x = o0; o.y = o1; o.z = o2; o.w = o3;
        reinterpret_cast<float4*>((float*)outv + (size_t)t * DMODEL)[tid] = o;
    }
}

// ---------------- GEMM: C = A(bf16) @ B(f32) (+bias) (softplus?) (+resid f32) ----------------
#define TM 128
#define TN 128
#define TK 16

template <bool OUT_BF16>
__global__ __launch_bounds__(256) void gemm_abf16(
    const ushort_t* __restrict__ A, const float* __restrict__ B,
    void* __restrict__ Cv, const float* __restrict__ bias,
    const float* __restrict__ resid,
    int M, int N, int K, int lda, int ldb, int ldc, int act)
{
    __shared__ float As[TK][TM];  // k-major (transposed)
    __shared__ float Bs[TK][TN];
    const int tid = threadIdx.x;
    const int row0 = blockIdx.y * TM;
    const int col0 = blockIdx.x * TN;
    const int tx = tid & 15;
    const int ty = tid >> 4;
    float acc[8][8];
#pragma unroll
    for (int i = 0; i < 8; ++i)
#pragma unroll
        for (int j = 0; j < 8; ++j) acc[i][j] = 0.0f;

    for (int k0 = 0; k0 < K; k0 += TK) {
        {
            const int row = tid >> 1;
            const int cg = (tid & 1) * 8;
            const uint4 raw = *reinterpret_cast<const uint4*>(
                &A[(size_t)(row0 + row) * lda + k0 + cg]);
            As[cg + 0][row] = lo16(raw.x);
            As[cg + 1][row] = hi16(raw.x);
            As[cg + 2][row] = lo16(raw.y);
            As[cg + 3][row] = hi16(raw.y);
            As[cg + 4][row] = lo16(raw.z);
            As[cg + 5][row] = hi16(raw.z);
            As[cg + 6][row] = lo16(raw.w);
            As[cg + 7][row] = hi16(raw.w);
        }
        {
            const int brow = tid >> 4;
            const int bcol = (tid & 15) * 8;
            float4 b0, b1;
            if (col0 + bcol < N) {
                b0 = *reinterpret_cast<const float4*>(
                    &B[(size_t)(k0 + brow) * ldb + col0 + bcol]);
                b1 = *reinterpret_cast<const float4*>(
                    &B[(size_t)(k0 + brow) * ldb + col0 + bcol + 4]);
            } else {
                b0 = make_float4(0.f, 0.f, 0.f, 0.f);
                b1 = b0;
            }
            *reinterpret_cast<float4*>(&Bs[brow][bcol]) = b0;
            *reinterpret_cast<float4*>(&Bs[brow][bcol + 4]) = b1;
        }
        __syncthreads();
#pragma unroll
        for (int k = 0; k < TK; ++k) {
            float a[8], b[8];
            *reinterpret_cast<float4*>(&a[0]) = *reinterpret_cast<const float4*>(&As[k][ty * 8]);
            *reinterpret_cast<float4*>(&a[4]) = *reinterpret_cast<const float4*>(&As[k][ty * 8 + 4]);
            *reinterpret_cast<float4*>(&b[0]) = *reinterpret_cast<const float4*>(&Bs[k][tx * 8]);
            *reinterpret_cast<float4*>(&b[4]) = *reinterpret_cast<const float4*>(&Bs[k][tx * 8 + 4]);
#pragma unroll
            for (int i = 0; i < 8; ++i)
#pragma unroll
                for (int j = 0; j < 8; ++j) acc[i][j] += a[i] * b[j];
        }
        __syncthreads();
    }

#pragma unroll
    for (int i = 0; i < 8; ++i) {
        const int r = row0 + ty * 8 + i;
#pragma unroll
        for (int jj = 0; jj < 2; ++jj) {
            const int c = col0 + tx * 8 + jj * 4;
            if (c >= N) continue;
            float v0 = acc[i][jj * 4 + 0];
            float v1 = acc[i][jj * 4 + 1];
            float v2 = acc[i][jj * 4 + 2];
            float v3 = acc[i][jj * 4 + 3];
            if (bias) {
                v0 += bias[c + 0]; v1 += bias[c + 1];
                v2 += bias[c + 2]; v3 += bias[c + 3];
            }
            if (act == 1) {  // softplus
                v0 = fmaxf(v0, 0.f) + log1pf(expf(-fabsf(v0)));
                v1 = fmaxf(v1, 0.f) + log1pf(expf(-fabsf(v1)));
                v2 = fmaxf(v2, 0.f) + log1pf(expf(-fabsf(v2)));
                v3 = fmaxf(v3, 0.f) + log1pf(expf(-fabsf(v3)));
            }
            if (resid) {
                const float4 rv = *reinterpret_cast<const float4*>(
                    &resid[(size_t)r * ldc + c]);
                v0 += rv.x; v1 += rv.y; v2 += rv.z; v3 += rv.w;
            }
            if (OUT_BF16) {
                ushort4 o;
                o.x = f2bf(v0); o.y = f2bf(v1); o.z = f2bf(v2); o.w = f2bf(v3);
                *reinterpret_cast<ushort4*>(&((ushort_t*)Cv)[(size_t)r * ldc + c]) = o;
            } else {
                float4 o; o.x = v0; o.y = v1; o.z = v2; o.w = v3;
                *reinterpret_cast<float4*>(&((float*)Cv)[(size_t)r * ldc + c]) = o;
            }
        }
    }
}

// ---------------- Causal depthwise conv (K=4) + bias + SiLU (bf16 in/out) ----------------
__global__ __launch_bounds__(256) void conv_silu_kernel(
    const ushort_t* __restrict__ xr, const float* __restrict__ w,
    const float* __restrict__ bcv, ushort_t* __restrict__ xi)
{
    const int idx = blockIdx.x * 256 + threadIdx.x;  // B*L*DINNER = 2^24
    const int c = idx & (DINNER - 1);
    const int l = (idx >> 11) & (SEQL - 1);
    const int b = idx >> 23;
    const float w0 = w[c * 4 + 0], w1 = w[c * 4 + 1], w2 = w[c * 4 + 2], w3 = w[c * 4 + 3];
    const size_t base = ((size_t)(b * SEQL + l)) * DINNER + c;
    float s = bcv[c];
    if (l >= 3) s += w0 * bf2f(xr[base - 3 * DINNER]);
    if (l >= 2) s += w1 * bf2f(xr[base - 2 * DINNER]);
    if (l >= 1) s += w2 * bf2f(xr[base - 1 * DINNER]);
    s += w3 * bf2f(xr[base]);
    const float sig = 1.0f / (1.0f + expf(-s));
    xi[base] = f2bf(s * sig);
}

// ---------------- Chunked selective scan ----------------
// Phase 1: per (b,d,chunk) compute chunk-local h_final (zero init) and S = sum(delta).
// Chunk decay product per state n is exp(An * S) since dA = exp(delta*An).
__global__ __launch_bounds__(256) void scan_phase1(
    const ushort_t* __restrict__ delta, const ushort_t* __restrict__ u_in,
    const ushort_t* __restrict__ xdbl, const float* __restrict__ A_log,
    float* __restrict__ hf,    // [B][NCHUNK][NSTATE][DINNER]
    float* __restrict__ Ssum)  // [B][NCHUNK][DINNER]
{
    const int d = blockIdx.x * 256 + threadIdx.x;
    const int c = blockIdx.y;
    const int b = blockIdx.z;
    float An[NSTATE];
#pragma unroll
    for (int n = 0; n < NSTATE; ++n) An[n] = -expf(A_log[d * NSTATE + n]);
    float h0 = 0.f, h1 = 0.f, h2 = 0.f, h3 = 0.f, S = 0.f;
    size_t idx_du = ((size_t)b * SEQL + (size_t)c * CHUNK) * DINNER + d;
    size_t idx_bc = ((size_t)b * SEQL + (size_t)c * CHUNK) * XDBLN + DTRANK;
    for (int l = 0; l < CHUNK; ++l) {
        const float dv = bf2f(delta[idx_du]);
        const float u  = bf2f(u_in[idx_du]);
        const uint4 bc = *reinterpret_cast<const uint4*>(&xdbl[idx_bc]);  // B0..3,C0..3
        const float dvu = dv * u;
        S += dv;
        h0 = expf(dv * An[0]) * h0 + dvu * lo16(bc.x);
        h1 = expf(dv * An[1]) * h1 + dvu * hi16(bc.x);
        h2 = expf(dv * An[2]) * h2 + dvu * lo16(bc.y);
        h3 = expf(dv * An[3]) * h3 + dvu * hi16(bc.y);
        idx_du += DINNER;
        idx_bc += XDBLN;
    }
    const size_t o = (((size_t)b * NCHUNK + c) * NSTATE) * DINNER + d;
    hf[o]              = h0;
    hf[o + DINNER]     = h1;
    hf[o + 2 * DINNER] = h2;
    hf[o + 3 * DINNER] = h3;
    Ssum[((size_t)b * NCHUNK + c) * DINNER + d] = S;
}

// Phase 3: reconstruct h_in by combining prior chunk summaries, then re-run the
// chunk recurrence emitting y, fused with D-skip and *silu(res). y in-place over u.
__global__ __launch_bounds__(256) void scan_phase3(
    const ushort_t* __restrict__ delta, const ushort_t* __restrict__ u_in,
    const ushort_t* __restrict__ xdbl, const ushort_t* __restrict__ res_in,
    const float* __restrict__ A_log, const float* __restrict__ D_skip,
    const float* __restrict__ hf, const float* __restrict__ Ssum,
    ushort_t* __restrict__ y_out)
{
    const int d = blockIdx.x * 256 + threadIdx.x;
    const int c = blockIdx.y;
    const int b = blockIdx.z;
    float An[NSTATE];
#pragma unroll
    for (int n = 0; n < NSTATE; ++n) An[n] = -expf(A_log[d * NSTATE + n]);
    const float Dk = D_skip[d];
    // combine chunk summaries 0..c-1: h = hf[j] + exp(An*S[j]) * h
    float h0 = 0.f, h1 = 0.f, h2 = 0.f, h3 = 0.f;
    for (int j = 0; j < c; ++j) {
        const float Sj = Ssum[((size_t)b * NCHUNK + j) * DINNER + d];
        const size_t o = (((size_t)b * NCHUNK + j) * NSTATE) * DINNER + d;
        h0 = hf[o]              + expf(An[0] * Sj) * h0;
        h1 = hf[o + DINNER]     + expf(An[1] * Sj) * h1;
        h2 = hf[o + 2 * DINNER] + expf(An[2] * Sj) * h2;
        h3 = hf[o + 3 * DINNER] + expf(An[3] * Sj) * h3;
    }
    // run the chunk with correct h_in, produce y
    size_t idx_du = ((size_t)b * SEQL + (size_t)c * CHUNK) * DINNER + d;
    size_t idx_bc = ((size_t)b * SEQL + (size_t)c * CHUNK) * XDBLN + DTRANK;
    for (int l = 0; l < CHUNK; ++l) {
        const float dv = bf2f(delta[idx_du]);
        const float u  = bf2f(u_in[idx_du]);
        const uint4 bc = *reinterpret_cast<const uint4*>(&xdbl[idx_bc]);
        const float dvu = dv * u;
        h0 = expf(dv * An[0]) * h0 + dvu * lo16(bc.x);
        h1 = expf(dv * An[1]) * h1 + dvu * hi16(bc.x);
        h2 = expf(dv * An[2]) * h2 + dvu * lo16(bc.y);
        h3 = expf(dv * An[3]) * h3 + dvu * hi16(bc.y);
        float y = h0 * lo16(bc.z) + h1 * hi16(bc.z) + h2 * lo16(bc.w) + h3 * hi16(bc.w);
        const float res = bf2f(res_in[idx_du]);
        const float sil = res / (1.0f + expf(-res));
        y_out[idx_du] = f2bf((y + u * Dk) * sil);
        idx_du += DINNER;
        idx_bc += XDBLN;
    }
}

// ---------------- Orchestration ----------------
extern "C" void kernel_launch(void* const* d_in, const int* in_sizes, int n_in,
                              void* d_out, int out_size, void* d_ws, size_t ws_size,
                              hipStream_t stream)
{
    const float* x        = (const float*)d_in[0];
    const float* in_proj  = (const float*)d_in[1];
    const float* conv_w   = (const float*)d_in[2];
    const float* conv_b   = (const float*)d_in[3];
    const float* x_proj   = (const float*)d_in[4];
    const float* dt_w     = (const float*)d_in[5];
    const float* dt_b     = (const float*)d_in[6];
    const float* A_log    = (const float*)d_in[7];
    const float* D_skip   = (const float*)d_in[8];
    const float* out_proj = (const float*)d_in[9];
    const float* norm_w   = (const float*)d_in[10];
    const float* norm_f_w = (const float*)d_in[11];
    float* out = (float*)d_out;

    // Workspace layout: 145.1 MB total (unchanged from passing round).
    char* p = (char*)d_ws;
    float*    x_cur = (float*)p;    p += (size_t)NTOK * DMODEL * 4;   // 33.5 MB
    ushort_t* xn    = (ushort_t*)p; p += (size_t)NTOK * DMODEL * 2;   // 16.8 MB (scan summaries reuse)
    ushort_t* xraw  = (ushort_t*)p; p += (size_t)NTOK * DINNER * 2;   // 33.5 MB (delta reuses)
    ushort_t* res   = (ushort_t*)p; p += (size_t)NTOK * DINNER * 2;   // 33.5 MB
    ushort_t* xi    = (ushort_t*)p; p += (size_t)NTOK * DINNER * 2;   // 33.5 MB (y in-place)
    ushort_t* xdbl  = (ushort_t*)p; p += (size_t)NTOK * XDBLN * 2;    //  1.2 MB
    const size_t need = (size_t)(p - (char*)d_ws);
    if (ws_size < need) return;
    ushort_t* delta = xraw;            // xraw dead after conv
    float* hf   = (float*)xn;          // 4 MB  [B][NCHUNK][NSTATE][DINNER] (xn dead after in_proj)
    float* Ssum = hf + (size_t)NB * NCHUNK * NSTATE * DINNER;  // 1 MB

    for (int i = 0; i < 2; ++i) {
        const float* x_in = (i == 0) ? x : x_cur;
        rmsnorm_kernel<true><<<NTOK, 256, 0, stream>>>(x_in, norm_w + (size_t)i * DMODEL, xn);
        {
            dim3 g(DINNER / TN, NTOK / TM);
            gemm_abf16<true><<<g, 256, 0, stream>>>(
                xn, in_proj + (size_t)i * DMODEL * 2 * DINNER, xraw, nullptr, nullptr,
                NTOK, DINNER, DMODEL, DMODEL, 2 * DINNER, DINNER, 0);
            gemm_abf16<true><<<g, 256, 0, stream>>>(
                xn, in_proj + (size_t)i * DMODEL * 2 * DINNER + DINNER, res, nullptr, nullptr,
                NTOK, DINNER, DMODEL, DMODEL, 2 * DINNER, DINNER, 0);
        }
        conv_silu_kernel<<<(NTOK * DINNER) / 256, 256, 0, stream>>>(
            xraw, conv_w + (size_t)i * DINNER * 4, conv_b + (size_t)i * DINNER, xi);
        {
            dim3 g(1, NTOK / TM);
            gemm_abf16<true><<<g, 256, 0, stream>>>(
                xi, x_proj + (size_t)i * DINNER * XDBLN, xdbl, nullptr, nullptr,
                NTOK, XDBLN, DINNER, DINNER, XDBLN, XDBLN, 0);
        }
        {
            dim3 g(DINNER / TN, NTOK / TM);
            gemm_abf16<true><<<g, 256, 0, stream>>>(
                xdbl, dt_w + (size_t)i * DTRANK * DINNER, delta, dt_b + (size_t)i * DINNER, nullptr,
                NTOK, DINNER, DTRANK, XDBLN, DINNER, DINNER, 1);
        }
        {
            dim3 g(DINNER / 256, NCHUNK, NB);
            scan_phase1<<<g, 256, 0, stream>>>(
                delta, xi, xdbl, A_log + (size_t)i * DINNER * NSTATE, hf, Ssum);
            scan_phase3<<<g, 256, 0, stream>>>(
                delta, xi, xdbl, res,
                A_log + (size_t)i * DINNER * NSTATE, D_skip + (size_t)i * DINNER,
                hf, Ssum, xi);
        }
        {
            dim3 g(DMODEL / TN, NTOK / TM);
            gemm_abf16<false><<<g, 256, 0, stream>>>(
                xi, out_proj + (size_t)i * DINNER * DMODEL, x_cur, nullptr, x_in,
                NTOK, DMODEL, DINNER, DINNER, DMODEL, DMODEL, 0);
        }
    }
    rmsnorm_kernel<false><<<NTOK, 256, 0, stream>>>(x_cur, norm_f_w, out);
}

// Round 4
// 935.999 us; speedup vs baseline: 12.4545x; 6.6206x over previous
//
#include <hip/hip_runtime.h>
#include <stdint.h>

#define DMODEL 1024
#define DINNER 2048
#define NSTATE 4
#define DTRANK 64
#define XDBLN  72
#define SEQL   4096
#define NB     2
#define NTOK   (NB * SEQL)
#define CHUNK  64
#define NCHUNK (SEQL / CHUNK)   // 64

typedef unsigned short ushort_t;
typedef __attribute__((ext_vector_type(8))) __bf16 bf16x8;
typedef __attribute__((ext_vector_type(4))) float f32x4;

__device__ __forceinline__ float bf2f(ushort_t h) {
    return __uint_as_float(((unsigned int)h) << 16);
}
__device__ __forceinline__ ushort_t f2bf(float f) {
    unsigned int u = __float_as_uint(f);
    u += 0x7fffu + ((u >> 16) & 1u);   // round-to-nearest-even
    return (ushort_t)(u >> 16);
}
__device__ __forceinline__ float lo16(unsigned int x) { return __uint_as_float(x << 16); }
__device__ __forceinline__ float hi16(unsigned int x) { return __uint_as_float(x & 0xffff0000u); }

// global -> LDS direct copy, 16 B per lane; lds base must be wave-uniform.
__device__ __forceinline__ void gload_lds16(const void* g, void* lds) {
    __builtin_amdgcn_global_load_lds(
        (const __attribute__((address_space(1))) unsigned int*)(uintptr_t)g,
        (__attribute__((address_space(3))) unsigned int*)(uintptr_t)lds,
        16, 0, 0);
}

// ---------------- RMSNorm: one block per token ----------------
template <bool OUT_BF16>
__global__ __launch_bounds__(256) void rmsnorm_kernel(
    const float* __restrict__ in, const float* __restrict__ w,
    void* __restrict__ outv)
{
    const int t = blockIdx.x;
    const int tid = threadIdx.x;
    const float4 v = reinterpret_cast<const float4*>(in + (size_t)t * DMODEL)[tid];
    float ss = v.x * v.x + v.y * v.y + v.z * v.z + v.w * v.w;
#pragma unroll
    for (int o = 32; o > 0; o >>= 1) ss += __shfl_xor(ss, o, 64);
    __shared__ float red[4];
    if ((tid & 63) == 0) red[tid >> 6] = ss;
    __syncthreads();
    const float total = red[0] + red[1] + red[2] + red[3];
    const float scale = rsqrtf(total * (1.0f / DMODEL) + 1e-5f);
    const float4 wv = reinterpret_cast<const float4*>(w)[tid];
    const float o0 = v.x * scale * wv.x;
    const float o1 = v.y * scale * wv.y;
    const float o2 = v.z * scale * wv.z;
    const float o3 = v.w * scale * wv.w;
    if (OUT_BF16) {
        ushort4 o;
        o.x = f2bf(o0); o.y = f2bf(o1); o.z = f2bf(o2); o.w = f2bf(o3);
        reinterpret_cast<ushort4*>((ushort_t*)outv + (size_t)t * DMODEL)[tid] = o;
    } else {
        float4 o; o.x = o0; o.y = o1; o.z = o2; o.w = o3;
        reinterpret_cast<float4*>((float*)outv + (size_t)t * DMODEL)[tid] = o;
    }
}

// ---------------- Weight prep: W[K][N] f32 -> Wt[Npad][K] bf16 (pad rows zeroed) ----------------
__global__ __launch_bounds__(256) void transpose_w(
    const float* __restrict__ in, ushort_t* __restrict__ out,
    int K, int N, int Npad)
{
    __shared__ float t[32][33];
    const int k0 = blockIdx.x * 32, n0 = blockIdx.y * 32;
    const int tx = threadIdx.x & 31, ty = threadIdx.x >> 5;  // 32 x 8
#pragma unroll
    for (int i = 0; i < 32; i += 8) {
        const int k = k0 + ty + i, n = n0 + tx;
        t[ty + i][tx] = (n < N) ? in[(size_t)k * N + n] : 0.f;
    }
    __syncthreads();
#pragma unroll
    for (int i = 0; i < 32; i += 8) {
        const int n = n0 + ty + i, k = k0 + tx;
        if (n < Npad) out[(size_t)n * K + k] = f2bf(t[tx][ty + i]);
    }
}

// ---------------- MFMA GEMM: C[M][N] = A(bf16,[M][lda]) @ Bt(bf16,[N][K])^T ----------------
// m97 structure: 128x128 tile, BK=32, 4 waves (2x2 of 64x64), global_load_lds width 16.
template <bool OUT_BF16, bool SOFTPLUS, bool RESID, bool NGUARD>
__global__ __launch_bounds__(256) void gemm_mfma(
    const ushort_t* __restrict__ A, const ushort_t* __restrict__ Bt,
    void* __restrict__ Cv, const float* __restrict__ bias,
    const float* __restrict__ resid,
    int N, int K, int lda, int ldc)
{
    __shared__ alignas(16) ushort_t As[128 * 32];
    __shared__ alignas(16) ushort_t Bs[128 * 32];
    const int tid = threadIdx.x;
    const int wv = tid >> 6, ln = tid & 63;
    const int wr = wv >> 1, wc = wv & 1;
    const int row0 = blockIdx.y * 128, col0 = blockIdx.x * 128;
    const int srow = ln >> 2;          // staging row within 16-row chunk
    const int ske  = (ln & 3) * 8;     // staging k-element offset
    const int fr = ln & 15, fq = ln >> 4;

    f32x4 acc[4][4] = {};

    for (int k0 = 0; k0 < K; k0 += 32) {
#pragma unroll
        for (int i = 0; i < 2; ++i) {
            const int chunk = wv * 2 + i;            // 0..7, wave-uniform
            const int r = chunk * 16 + srow;         // 0..127
            gload_lds16(A  + (size_t)(row0 + r) * lda + k0 + ske, (char*)As + chunk * 1024);
            gload_lds16(Bt + (size_t)(col0 + r) * K   + k0 + ske, (char*)Bs + chunk * 1024);
        }
        asm volatile("s_waitcnt vmcnt(0)" ::: "memory");
        __syncthreads();
        bf16x8 af[4], bf[4];
#pragma unroll
        for (int mi = 0; mi < 4; ++mi)
            af[mi] = *(const bf16x8*)(As + (wr * 64 + mi * 16 + fr) * 32 + fq * 8);
#pragma unroll
        for (int ni = 0; ni < 4; ++ni)
            bf[ni] = *(const bf16x8*)(Bs + (wc * 64 + ni * 16 + fr) * 32 + fq * 8);
#pragma unroll
        for (int mi = 0; mi < 4; ++mi)
#pragma unroll
            for (int ni = 0; ni < 4; ++ni)
                acc[mi][ni] = __builtin_amdgcn_mfma_f32_16x16x32_bf16(
                    af[mi], bf[ni], acc[mi][ni], 0, 0, 0);
        __syncthreads();
    }

#pragma unroll
    for (int mi = 0; mi < 4; ++mi) {
#pragma unroll
        for (int ni = 0; ni < 4; ++ni) {
            const int c = col0 + wc * 64 + ni * 16 + fr;
            if (NGUARD && c >= N) continue;
            const float b = SOFTPLUS ? bias[c] : 0.f;
#pragma unroll
            for (int r = 0; r < 4; ++r) {
                const int rr = row0 + wr * 64 + mi * 16 + fq * 4 + r;
                float v = acc[mi][ni][r];
                if (SOFTPLUS) {
                    v += b;
                    v = fmaxf(v, 0.f) + log1pf(expf(-fabsf(v)));
                }
                if (RESID) v += resid[(size_t)rr * ldc + c];
                if (OUT_BF16) ((ushort_t*)Cv)[(size_t)rr * ldc + c] = f2bf(v);
                else          ((float*)Cv)[(size_t)rr * ldc + c]   = v;
            }
        }
    }
}

// ---------------- Causal depthwise conv (K=4) + bias + SiLU (bf16 in/out) ----------------
__global__ __launch_bounds__(256) void conv_silu_kernel(
    const ushort_t* __restrict__ xr, const float* __restrict__ w,
    const float* __restrict__ bcv, ushort_t* __restrict__ xi)
{
    const int idx = blockIdx.x * 256 + threadIdx.x;  // B*L*DINNER = 2^24
    const int c = idx & (DINNER - 1);
    const int l = (idx >> 11) & (SEQL - 1);
    const int b = idx >> 23;
    const float w0 = w[c * 4 + 0], w1 = w[c * 4 + 1], w2 = w[c * 4 + 2], w3 = w[c * 4 + 3];
    const size_t base = ((size_t)(b * SEQL + l)) * DINNER + c;
    float s = bcv[c];
    if (l >= 3) s += w0 * bf2f(xr[base - 3 * DINNER]);
    if (l >= 2) s += w1 * bf2f(xr[base - 2 * DINNER]);
    if (l >= 1) s += w2 * bf2f(xr[base - 1 * DINNER]);
    s += w3 * bf2f(xr[base]);
    const float sig = 1.0f / (1.0f + expf(-s));
    xi[base] = f2bf(s * sig);
}

// ---------------- Chunked selective scan ----------------
__global__ __launch_bounds__(256) void scan_phase1(
    const ushort_t* __restrict__ delta, const ushort_t* __restrict__ u_in,
    const ushort_t* __restrict__ xdbl, const float* __restrict__ A_log,
    float* __restrict__ hf,    // [B][NCHUNK][NSTATE][DINNER]
    float* __restrict__ Ssum)  // [B][NCHUNK][DINNER]
{
    const int d = blockIdx.x * 256 + threadIdx.x;
    const int c = blockIdx.y;
    const int b = blockIdx.z;
    float An[NSTATE];
#pragma unroll
    for (int n = 0; n < NSTATE; ++n) An[n] = -expf(A_log[d * NSTATE + n]);
    float h0 = 0.f, h1 = 0.f, h2 = 0.f, h3 = 0.f, S = 0.f;
    size_t idx_du = ((size_t)b * SEQL + (size_t)c * CHUNK) * DINNER + d;
    size_t idx_bc = ((size_t)b * SEQL + (size_t)c * CHUNK) * XDBLN + DTRANK;
    for (int l = 0; l < CHUNK; ++l) {
        const float dv = bf2f(delta[idx_du]);
        const float u  = bf2f(u_in[idx_du]);
        const uint4 bc = *reinterpret_cast<const uint4*>(&xdbl[idx_bc]);
        const float dvu = dv * u;
        S += dv;
        h0 = expf(dv * An[0]) * h0 + dvu * lo16(bc.x);
        h1 = expf(dv * An[1]) * h1 + dvu * hi16(bc.x);
        h2 = expf(dv * An[2]) * h2 + dvu * lo16(bc.y);
        h3 = expf(dv * An[3]) * h3 + dvu * hi16(bc.y);
        idx_du += DINNER;
        idx_bc += XDBLN;
    }
    const size_t o = (((size_t)b * NCHUNK + c) * NSTATE) * DINNER + d;
    hf[o]              = h0;
    hf[o + DINNER]     = h1;
    hf[o + 2 * DINNER] = h2;
    hf[o + 3 * DINNER] = h3;
    Ssum[((size_t)b * NCHUNK + c) * DINNER + d] = S;
}

__global__ __launch_bounds__(256) void scan_phase3(
    const ushort_t* __restrict__ delta, const ushort_t* __restrict__ u_in,
    const ushort_t* __restrict__ xdbl, const ushort_t* __restrict__ res_in,
    const float* __restrict__ A_log, const float* __restrict__ D_skip,
    const float* __restrict__ hf, const float* __restrict__ Ssum,
    ushort_t* __restrict__ y_out)
{
    const int d = blockIdx.x * 256 + threadIdx.x;
    const int c = blockIdx.y;
    const int b = blockIdx.z;
    float An[NSTATE];
#pragma unroll
    for (int n = 0; n < NSTATE; ++n) An[n] = -expf(A_log[d * NSTATE + n]);
    const float Dk = D_skip[d];
    float h0 = 0.f, h1 = 0.f, h2 = 0.f, h3 = 0.f;
    for (int j = 0; j < c; ++j) {
        const float Sj = Ssum[((size_t)b * NCHUNK + j) * DINNER + d];
        const size_t o = (((size_t)b * NCHUNK + j) * NSTATE) * DINNER + d;
        h0 = hf[o]              + expf(An[0] * Sj) * h0;
        h1 = hf[o + DINNER]     + expf(An[1] * Sj) * h1;
        h2 = hf[o + 2 * DINNER] + expf(An[2] * Sj) * h2;
        h3 = hf[o + 3 * DINNER] + expf(An[3] * Sj) * h3;
    }
    size_t idx_du = ((size_t)b * SEQL + (size_t)c * CHUNK) * DINNER + d;
    size_t idx_bc = ((size_t)b * SEQL + (size_t)c * CHUNK) * XDBLN + DTRANK;
    for (int l = 0; l < CHUNK; ++l) {
        const float dv = bf2f(delta[idx_du]);
        const float u  = bf2f(u_in[idx_du]);
        const uint4 bc = *reinterpret_cast<const uint4*>(&xdbl[idx_bc]);
        const float dvu = dv * u;
        h0 = expf(dv * An[0]) * h0 + dvu * lo16(bc.x);
        h1 = expf(dv * An[1]) * h1 + dvu * hi16(bc.x);
        h2 = expf(dv * An[2]) * h2 + dvu * lo16(bc.y);
        h3 = expf(dv * An[3]) * h3 + dvu * hi16(bc.y);
        float y = h0 * lo16(bc.z) + h1 * hi16(bc.z) + h2 * lo16(bc.w) + h3 * hi16(bc.w);
        const float res = bf2f(res_in[idx_du]);
        const float sil = res / (1.0f + expf(-res));
        y_out[idx_du] = f2bf((y + u * Dk) * sil);
        idx_du += DINNER;
        idx_bc += XDBLN;
    }
}

// ---------------- Orchestration ----------------
extern "C" void kernel_launch(void* const* d_in, const int* in_sizes, int n_in,
                              void* d_out, int out_size, void* d_ws, size_t ws_size,
                              hipStream_t stream)
{
    const float* x        = (const float*)d_in[0];
    const float* in_proj  = (const float*)d_in[1];
    const float* conv_w   = (const float*)d_in[2];
    const float* conv_b   = (const float*)d_in[3];
    const float* x_proj   = (const float*)d_in[4];
    const float* dt_w     = (const float*)d_in[5];
    const float* dt_b     = (const float*)d_in[6];
    const float* A_log    = (const float*)d_in[7];
    const float* D_skip   = (const float*)d_in[8];
    const float* out_proj = (const float*)d_in[9];
    const float* norm_w   = (const float*)d_in[10];
    const float* norm_f_w = (const float*)d_in[11];
    float* out = (float*)d_out;

    // Workspace layout: ~178.8 MB total (all chunks 16B-aligned).
    char* p = (char*)d_ws;
    float*    x_cur = (float*)p;    p += (size_t)NTOK * DMODEL * 4;    // 33.5 MB
    ushort_t* xn    = (ushort_t*)p; p += (size_t)NTOK * DMODEL * 2;    // 16.8 MB (hf/Ssum reuse)
    ushort_t* xraw  = (ushort_t*)p; p += (size_t)NTOK * DINNER * 2;    // 33.5 MB (delta reuses)
    ushort_t* res   = (ushort_t*)p; p += (size_t)NTOK * DINNER * 2;    // 33.5 MB
    ushort_t* xi    = (ushort_t*)p; p += (size_t)NTOK * DINNER * 2;    // 33.5 MB (y in-place)
    ushort_t* xdbl  = (ushort_t*)p; p += (size_t)NTOK * XDBLN * 2;     //  1.2 MB
    ushort_t* w_inT  = (ushort_t*)p; p += (size_t)2 * 2 * DINNER * DMODEL * 2;  // 16.8 MB [4096][1024] x2
    ushort_t* w_xpT  = (ushort_t*)p; p += (size_t)2 * 128 * DINNER * 2;         //  1.0 MB [128][2048] x2
    ushort_t* w_dtT  = (ushort_t*)p; p += (size_t)2 * DINNER * DTRANK * 2;      //  0.5 MB [2048][64] x2
    ushort_t* w_outT = (ushort_t*)p; p += (size_t)2 * DMODEL * DINNER * 2;      //  8.4 MB [1024][2048] x2
    const size_t need = (size_t)(p - (char*)d_ws);
    if (ws_size < need) return;  // clean diagnostic failure instead of page fault
    ushort_t* delta = xraw;
    float* hf   = (float*)xn;
    float* Ssum = hf + (size_t)NB * NCHUNK * NSTATE * DINNER;

    // ---- weight prep (8 small transposes) ----
    for (int i = 0; i < 2; ++i) {
        transpose_w<<<dim3(DMODEL / 32, (2 * DINNER) / 32), 256, 0, stream>>>(
            in_proj + (size_t)i * DMODEL * 2 * DINNER,
            w_inT + (size_t)i * 2 * DINNER * DMODEL, DMODEL, 2 * DINNER, 2 * DINNER);
        transpose_w<<<dim3(DINNER / 32, 128 / 32), 256, 0, stream>>>(
            x_proj + (size_t)i * DINNER * XDBLN,
            w_xpT + (size_t)i * 128 * DINNER, DINNER, XDBLN, 128);
        transpose_w<<<dim3(DTRANK / 32, DINNER / 32), 256, 0, stream>>>(
            dt_w + (size_t)i * DTRANK * DINNER,
            w_dtT + (size_t)i * DINNER * DTRANK, DTRANK, DINNER, DINNER);
        transpose_w<<<dim3(DINNER / 32, DMODEL / 32), 256, 0, stream>>>(
            out_proj + (size_t)i * DINNER * DMODEL,
            w_outT + (size_t)i * DMODEL * DINNER, DINNER, DMODEL, DMODEL);
    }

    for (int i = 0; i < 2; ++i) {
        const float* x_in = (i == 0) ? x : x_cur;
        rmsnorm_kernel<true><<<NTOK, 256, 0, stream>>>(x_in, norm_w + (size_t)i * DMODEL, xn);
        // xraw / res = xn @ in_proj halves  (M=8192, N=2048, K=1024)
        gemm_mfma<true, false, false, false><<<dim3(DINNER / 128, NTOK / 128), 256, 0, stream>>>(
            xn, w_inT + (size_t)i * 2 * DINNER * DMODEL, xraw,
            nullptr, nullptr, DINNER, DMODEL, DMODEL, DINNER);
        gemm_mfma<true, false, false, false><<<dim3(DINNER / 128, NTOK / 128), 256, 0, stream>>>(
            xn, w_inT + (size_t)i * 2 * DINNER * DMODEL + (size_t)DINNER * DMODEL, res,
            nullptr, nullptr, DINNER, DMODEL, DMODEL, DINNER);
        conv_silu_kernel<<<(NTOK * DINNER) / 256, 256, 0, stream>>>(
            xraw, conv_w + (size_t)i * DINNER * 4, conv_b + (size_t)i * DINNER, xi);
        // xdbl = xi @ x_proj  (N=72, guarded)
        gemm_mfma<true, false, false, true><<<dim3(1, NTOK / 128), 256, 0, stream>>>(
            xi, w_xpT + (size_t)i * 128 * DINNER, xdbl,
            nullptr, nullptr, XDBLN, DINNER, DINNER, XDBLN);
        // delta = softplus(xdbl[:, :64] @ dt_w + dt_b)
        gemm_mfma<true, true, false, false><<<dim3(DINNER / 128, NTOK / 128), 256, 0, stream>>>(
            xdbl, w_dtT + (size_t)i * DINNER * DTRANK, delta,
            dt_b + (size_t)i * DINNER, nullptr, DINNER, DTRANK, XDBLN, DINNER);
        // selective scan
        {
            dim3 g(DINNER / 256, NCHUNK, NB);
            scan_phase1<<<g, 256, 0, stream>>>(
                delta, xi, xdbl, A_log + (size_t)i * DINNER * NSTATE, hf, Ssum);
            scan_phase3<<<g, 256, 0, stream>>>(
                delta, xi, xdbl, res,
                A_log + (size_t)i * DINNER * NSTATE, D_skip + (size_t)i * DINNER,
                hf, Ssum, xi);
        }
        // x_cur = y @ out_proj + x_in   (f32 out, resid fused)
        gemm_mfma<false, false, true, false><<<dim3(DMODEL / 128, NTOK / 128), 256, 0, stream>>>(
            xi, w_outT + (size_t)i * DMODEL * DINNER, x_cur,
            nullptr, x_in, DMODEL, DINNER, DINNER, DMODEL);
    }
    rmsnorm_kernel<false><<<NTOK, 256, 0, stream>>>(x_cur, norm_f_w, out);
}

// Round 5
// 930.538 us; speedup vs baseline: 12.5276x; 1.0059x over previous
//
#include <hip/hip_runtime.h>
#include <stdint.h>

#define DMODEL 1024
#define DINNER 2048
#define NSTATE 4
#define DTRANK 64
#define XDBLN  72
#define SEQL   4096
#define NB     2
#define NTOK   (NB * SEQL)
#define CHUNK  32
#define NCHUNK (SEQL / CHUNK)   // 128

typedef unsigned short ushort_t;
typedef __attribute__((ext_vector_type(8))) __bf16 bf16x8;
typedef __attribute__((ext_vector_type(4))) float f32x4;

__device__ __forceinline__ float bf2f(ushort_t h) {
    return __uint_as_float(((unsigned int)h) << 16);
}
__device__ __forceinline__ ushort_t f2bf(float f) {
    unsigned int u = __float_as_uint(f);
    u += 0x7fffu + ((u >> 16) & 1u);   // round-to-nearest-even
    return (ushort_t)(u >> 16);
}
__device__ __forceinline__ float lo16(unsigned int x) { return __uint_as_float(x << 16); }
__device__ __forceinline__ float hi16(unsigned int x) { return __uint_as_float(x & 0xffff0000u); }

// global -> LDS direct copy, 16 B per lane; lds base must be wave-uniform.
__device__ __forceinline__ void gload_lds16(const void* g, void* lds) {
    __builtin_amdgcn_global_load_lds(
        (const __attribute__((address_space(1))) unsigned int*)(uintptr_t)g,
        (__attribute__((address_space(3))) unsigned int*)(uintptr_t)lds,
        16, 0, 0);
}

// ---------------- RMSNorm: one block per token ----------------
template <bool OUT_BF16>
__global__ __launch_bounds__(256) void rmsnorm_kernel(
    const float* __restrict__ in, const float* __restrict__ w,
    void* __restrict__ outv)
{
    const int t = blockIdx.x;
    const int tid = threadIdx.x;
    const float4 v = reinterpret_cast<const float4*>(in + (size_t)t * DMODEL)[tid];
    float ss = v.x * v.x + v.y * v.y + v.z * v.z + v.w * v.w;
#pragma unroll
    for (int o = 32; o > 0; o >>= 1) ss += __shfl_xor(ss, o, 64);
    __shared__ float red[4];
    if ((tid & 63) == 0) red[tid >> 6] = ss;
    __syncthreads();
    const float total = red[0] + red[1] + red[2] + red[3];
    const float scale = rsqrtf(total * (1.0f / DMODEL) + 1e-5f);
    const float4 wv = reinterpret_cast<const float4*>(w)[tid];
    const float o0 = v.x * scale * wv.x;
    const float o1 = v.y * scale * wv.y;
    const float o2 = v.z * scale * wv.z;
    const float o3 = v.w * scale * wv.w;
    if (OUT_BF16) {
        ushort4 o;
        o.x = f2bf(o0); o.y = f2bf(o1); o.z = f2bf(o2); o.w = f2bf(o3);
        reinterpret_cast<ushort4*>((ushort_t*)outv + (size_t)t * DMODEL)[tid] = o;
    } else {
        float4 o; o.x = o0; o.y = o1; o.z = o2; o.w = o3;
        reinterpret_cast<float4*>((float*)outv + (size_t)t * DMODEL)[tid] = o;
    }
}

// ---------------- Weight prep: W[K][N] f32 -> Wt[Npad][K] bf16 (pad rows zeroed) ----------------
__global__ __launch_bounds__(256) void transpose_w(
    const float* __restrict__ in, ushort_t* __restrict__ out,
    int K, int N, int Npad)
{
    __shared__ float t[32][33];
    const int k0 = blockIdx.x * 32, n0 = blockIdx.y * 32;
    const int tx = threadIdx.x & 31, ty = threadIdx.x >> 5;  // 32 x 8
#pragma unroll
    for (int i = 0; i < 32; i += 8) {
        const int k = k0 + ty + i, n = n0 + tx;
        t[ty + i][tx] = (n < N) ? in[(size_t)k * N + n] : 0.f;
    }
    __syncthreads();
#pragma unroll
    for (int i = 0; i < 32; i += 8) {
        const int n = n0 + ty + i, k = k0 + tx;
        if (n < Npad) out[(size_t)n * K + k] = f2bf(t[tx][ty + i]);
    }
}

// ---------------- MFMA GEMM: C[M][N] = A(bf16,[M][lda]) @ Bt(bf16,[N][ldb])^T ----------------
// m97 structure: 128x128 tile, BK=32, 4 waves (2x2 of 64x64), global_load_lds width 16,
// XCD-aware bijective block swizzle (all grids have nwg % 8 == 0).
template <bool OUT_BF16, bool SOFTPLUS, bool RESID, bool NGUARD>
__global__ __launch_bounds__(256) void gemm_mfma(
    const ushort_t* __restrict__ A, const ushort_t* __restrict__ Bt,
    void* __restrict__ Cv, const float* __restrict__ bias,
    const float* __restrict__ resid,
    int N, int K, int lda, int ldb, int ldc)
{
    __shared__ alignas(16) ushort_t As[128 * 32];
    __shared__ alignas(16) ushort_t Bs[128 * 32];
    const int tid = threadIdx.x;
    const int wv = tid >> 6, ln = tid & 63;
    const int wr = wv >> 1, wc = wv & 1;
    // XCD swizzle
    const int gx = gridDim.x;
    const int nwg = gx * gridDim.y;
    int wg = blockIdx.y * gx + blockIdx.x;
    wg = (wg & 7) * (nwg >> 3) + (wg >> 3);
    const int row0 = (wg / gx) * 128, col0 = (wg % gx) * 128;

    const int srow = ln >> 2;          // staging row within 16-row chunk
    const int ske  = (ln & 3) * 8;     // staging k-element offset
    const int fr = ln & 15, fq = ln >> 4;

    f32x4 acc[4][4] = {};

    for (int k0 = 0; k0 < K; k0 += 32) {
#pragma unroll
        for (int i = 0; i < 2; ++i) {
            const int chunk = wv * 2 + i;            // 0..7, wave-uniform
            const int r = chunk * 16 + srow;         // 0..127
            gload_lds16(A  + (size_t)(row0 + r) * lda + k0 + ske, (char*)As + chunk * 1024);
            gload_lds16(Bt + (size_t)(col0 + r) * ldb + k0 + ske, (char*)Bs + chunk * 1024);
        }
        asm volatile("s_waitcnt vmcnt(0)" ::: "memory");
        __syncthreads();
        bf16x8 af[4], bf[4];
#pragma unroll
        for (int mi = 0; mi < 4; ++mi)
            af[mi] = *(const bf16x8*)(As + (wr * 64 + mi * 16 + fr) * 32 + fq * 8);
#pragma unroll
        for (int ni = 0; ni < 4; ++ni)
            bf[ni] = *(const bf16x8*)(Bs + (wc * 64 + ni * 16 + fr) * 32 + fq * 8);
#pragma unroll
        for (int mi = 0; mi < 4; ++mi)
#pragma unroll
            for (int ni = 0; ni < 4; ++ni)
                acc[mi][ni] = __builtin_amdgcn_mfma_f32_16x16x32_bf16(
                    af[mi], bf[ni], acc[mi][ni], 0, 0, 0);
        __syncthreads();
    }

#pragma unroll
    for (int mi = 0; mi < 4; ++mi) {
#pragma unroll
        for (int ni = 0; ni < 4; ++ni) {
            const int c = col0 + wc * 64 + ni * 16 + fr;
            if (NGUARD && c >= N) continue;
            const float b = SOFTPLUS ? bias[c] : 0.f;
#pragma unroll
            for (int r = 0; r < 4; ++r) {
                const int rr = row0 + wr * 64 + mi * 16 + fq * 4 + r;
                float v = acc[mi][ni][r];
                if (SOFTPLUS) {
                    v += b;
                    v = fmaxf(v, 0.f) + log1pf(expf(-fabsf(v)));
                }
                if (RESID) v += resid[(size_t)rr * ldc + c];
                if (OUT_BF16) ((ushort_t*)Cv)[(size_t)rr * ldc + c] = f2bf(v);
                else          ((float*)Cv)[(size_t)rr * ldc + c]   = v;
            }
        }
    }
}

// ---------------- x_proj split-K reduce: xdbl = f2bf(sum of 4 partials) ----------------
__global__ __launch_bounds__(128) void xp_reduce(
    const float* __restrict__ part, ushort_t* __restrict__ xdbl)
{
    const int t = blockIdx.x;          // token
    const int j = threadIdx.x;         // 0..127
    if (j >= XDBLN) return;
    const size_t o = (size_t)t * 128 + j;
    const size_t stride = (size_t)NTOK * 128;
    const float s = part[o] + part[o + stride] + part[o + 2 * stride] + part[o + 3 * stride];
    xdbl[(size_t)t * XDBLN + j] = f2bf(s);
}

// ---------------- Causal depthwise conv (K=4) + bias + SiLU (bf16 in/out) ----------------
__global__ __launch_bounds__(256) void conv_silu_kernel(
    const ushort_t* __restrict__ xr, const float* __restrict__ w,
    const float* __restrict__ bcv, ushort_t* __restrict__ xi)
{
    const int idx = blockIdx.x * 256 + threadIdx.x;  // B*L*DINNER = 2^24
    const int c = idx & (DINNER - 1);
    const int l = (idx >> 11) & (SEQL - 1);
    const int b = idx >> 23;
    const float w0 = w[c * 4 + 0], w1 = w[c * 4 + 1], w2 = w[c * 4 + 2], w3 = w[c * 4 + 3];
    const size_t base = ((size_t)(b * SEQL + l)) * DINNER + c;
    float s = bcv[c];
    if (l >= 3) s += w0 * bf2f(xr[base - 3 * DINNER]);
    if (l >= 2) s += w1 * bf2f(xr[base - 2 * DINNER]);
    if (l >= 1) s += w2 * bf2f(xr[base - 1 * DINNER]);
    s += w3 * bf2f(xr[base]);
    const float sig = 1.0f / (1.0f + expf(-s));
    xi[base] = f2bf(s * sig);
}

// ---------------- Chunked selective scan (CHUNK=32, 2 d-channels per thread) ----------------
// Phase 1: per (b,chunk,d-pair) chunk-local h_final (zero init) + S = sum(delta).
__global__ __launch_bounds__(256) void scan_phase1(
    const ushort_t* __restrict__ delta, const ushort_t* __restrict__ u_in,
    const ushort_t* __restrict__ xdbl, const float* __restrict__ A_log,
    float* __restrict__ hf,    // [B][NCHUNK][NSTATE][DINNER]
    float* __restrict__ Ssum)  // [B][NCHUNK][DINNER]
{
    const int d0 = (blockIdx.x * 256 + threadIdx.x) * 2;
    const int c = blockIdx.y;
    const int b = blockIdx.z;
    float An0[NSTATE], An1[NSTATE];
#pragma unroll
    for (int n = 0; n < NSTATE; ++n) {
        An0[n] = -expf(A_log[d0 * NSTATE + n]);
        An1[n] = -expf(A_log[(d0 + 1) * NSTATE + n]);
    }
    float h0[NSTATE] = {}, h1[NSTATE] = {};
    float S0 = 0.f, S1 = 0.f;
    size_t idx = ((size_t)b * SEQL + (size_t)c * CHUNK) * DINNER + d0;
    size_t idx_bc = ((size_t)b * SEQL + (size_t)c * CHUNK) * XDBLN + DTRANK;
    for (int l = 0; l < CHUNK; ++l) {
        const unsigned int dv2 = *reinterpret_cast<const unsigned int*>(delta + idx);
        const unsigned int u2  = *reinterpret_cast<const unsigned int*>(u_in + idx);
        const uint4 bc = *reinterpret_cast<const uint4*>(&xdbl[idx_bc]);
        const float dv0 = lo16(dv2), dv1 = hi16(dv2);
        const float u0 = lo16(u2), u1 = hi16(u2);
        const float Bv[NSTATE] = { lo16(bc.x), hi16(bc.x), lo16(bc.y), hi16(bc.y) };
        const float dvu0 = dv0 * u0, dvu1 = dv1 * u1;
        S0 += dv0; S1 += dv1;
#pragma unroll
        for (int n = 0; n < NSTATE; ++n) {
            h0[n] = expf(dv0 * An0[n]) * h0[n] + dvu0 * Bv[n];
            h1[n] = expf(dv1 * An1[n]) * h1[n] + dvu1 * Bv[n];
        }
        idx += DINNER;
        idx_bc += XDBLN;
    }
    const size_t o = (((size_t)b * NCHUNK + c) * NSTATE) * DINNER + d0;
#pragma unroll
    for (int n = 0; n < NSTATE; ++n) {
        float2 v; v.x = h0[n]; v.y = h1[n];
        *reinterpret_cast<float2*>(hf + o + (size_t)n * DINNER) = v;
    }
    float2 sv; sv.x = S0; sv.y = S1;
    *reinterpret_cast<float2*>(Ssum + ((size_t)b * NCHUNK + c) * DINNER + d0) = sv;
}

// Phase 2: in-place convert chunk-local finals -> incoming prefixes.
// hf[b][c][n][d] := h_in at chunk c start.  16384 threads, serial over 128 chunks.
__global__ __launch_bounds__(256) void scan_phase2(
    float* __restrict__ hf, const float* __restrict__ Ssum,
    const float* __restrict__ A_log)
{
    const int gid = blockIdx.x * 256 + threadIdx.x;  // B*NSTATE*DINNER = 16384
    const int d = gid & (DINNER - 1);
    const int n = (gid >> 11) & 3;
    const int b = gid >> 13;
    const float An = -expf(A_log[d * NSTATE + n]);
    float hin = 0.f;
    for (int c = 0; c < NCHUNK; ++c) {
        const size_t oh = (((size_t)b * NCHUNK + c) * NSTATE + n) * DINNER + d;
        const float hl = hf[oh];
        const float Sc = Ssum[((size_t)b * NCHUNK + c) * DINNER + d];
        hf[oh] = hin;
        hin = hl + expf(An * Sc) * hin;
    }
}

// Phase 3: load h_in, run chunk recurrence, emit y fused with D-skip and *silu(res).
__global__ __launch_bounds__(256) void scan_phase3(
    const ushort_t* __restrict__ delta, const ushort_t* __restrict__ u_in,
    const ushort_t* __restrict__ xdbl, const ushort_t* __restrict__ res_in,
    const float* __restrict__ A_log, const float* __restrict__ D_skip,
    const float* __restrict__ hf, ushort_t* __restrict__ y_out)
{
    const int d0 = (blockIdx.x * 256 + threadIdx.x) * 2;
    const int c = blockIdx.y;
    const int b = blockIdx.z;
    float An0[NSTATE], An1[NSTATE];
#pragma unroll
    for (int n = 0; n < NSTATE; ++n) {
        An0[n] = -expf(A_log[d0 * NSTATE + n]);
        An1[n] = -expf(A_log[(d0 + 1) * NSTATE + n]);
    }
    const float Dk0 = D_skip[d0], Dk1 = D_skip[d0 + 1];
    float h0[NSTATE], h1[NSTATE];
    const size_t o = (((size_t)b * NCHUNK + c) * NSTATE) * DINNER + d0;
#pragma unroll
    for (int n = 0; n < NSTATE; ++n) {
        const float2 v = *reinterpret_cast<const float2*>(hf + o + (size_t)n * DINNER);
        h0[n] = v.x; h1[n] = v.y;
    }
    size_t idx = ((size_t)b * SEQL + (size_t)c * CHUNK) * DINNER + d0;
    size_t idx_bc = ((size_t)b * SEQL + (size_t)c * CHUNK) * XDBLN + DTRANK;
    for (int l = 0; l < CHUNK; ++l) {
        const unsigned int dv2 = *reinterpret_cast<const unsigned int*>(delta + idx);
        const unsigned int u2  = *reinterpret_cast<const unsigned int*>(u_in + idx);
        const unsigned int r2  = *reinterpret_cast<const unsigned int*>(res_in + idx);
        const uint4 bc = *reinterpret_cast<const uint4*>(&xdbl[idx_bc]);
        const float dv0 = lo16(dv2), dv1 = hi16(dv2);
        const float u0 = lo16(u2), u1 = hi16(u2);
        const float Bv[NSTATE] = { lo16(bc.x), hi16(bc.x), lo16(bc.y), hi16(bc.y) };
        const float Cv[NSTATE] = { lo16(bc.z), hi16(bc.z), lo16(bc.w), hi16(bc.w) };
        const float dvu0 = dv0 * u0, dvu1 = dv1 * u1;
        float y0 = 0.f, y1 = 0.f;
#pragma unroll
        for (int n = 0; n < NSTATE; ++n) {
            h0[n] = expf(dv0 * An0[n]) * h0[n] + dvu0 * Bv[n];
            h1[n] = expf(dv1 * An1[n]) * h1[n] + dvu1 * Bv[n];
            y0 += h0[n] * Cv[n];
            y1 += h1[n] * Cv[n];
        }
        const float res0 = lo16(r2), res1 = hi16(r2);
        const float sil0 = res0 / (1.0f + expf(-res0));
        const float sil1 = res1 / (1.0f + expf(-res1));
        const ushort_t ya = f2bf((y0 + u0 * Dk0) * sil0);
        const ushort_t yb = f2bf((y1 + u1 * Dk1) * sil1);
        *reinterpret_cast<unsigned int*>(y_out + idx) =
            (unsigned int)ya | ((unsigned int)yb << 16);
        idx += DINNER;
        idx_bc += XDBLN;
    }
}

// ---------------- Orchestration ----------------
extern "C" void kernel_launch(void* const* d_in, const int* in_sizes, int n_in,
                              void* d_out, int out_size, void* d_ws, size_t ws_size,
                              hipStream_t stream)
{
    const float* x        = (const float*)d_in[0];
    const float* in_proj  = (const float*)d_in[1];
    const float* conv_w   = (const float*)d_in[2];
    const float* conv_b   = (const float*)d_in[3];
    const float* x_proj   = (const float*)d_in[4];
    const float* dt_w     = (const float*)d_in[5];
    const float* dt_b     = (const float*)d_in[6];
    const float* A_log    = (const float*)d_in[7];
    const float* D_skip   = (const float*)d_in[8];
    const float* out_proj = (const float*)d_in[9];
    const float* norm_w   = (const float*)d_in[10];
    const float* norm_f_w = (const float*)d_in[11];
    float* out = (float*)d_out;

    // Workspace layout: ~178.8 MB total (all chunks 16B-aligned).
    char* p = (char*)d_ws;
    float*    x_cur = (float*)p;    p += (size_t)NTOK * DMODEL * 4;    // 33.5 MB
    ushort_t* xn    = (ushort_t*)p; p += (size_t)NTOK * DMODEL * 2;    // 16.8 MB (xp partials / hf+Ssum reuse)
    ushort_t* xraw  = (ushort_t*)p; p += (size_t)NTOK * DINNER * 2;    // 33.5 MB (delta reuses)
    ushort_t* res   = (ushort_t*)p; p += (size_t)NTOK * DINNER * 2;    // 33.5 MB
    ushort_t* xi    = (ushort_t*)p; p += (size_t)NTOK * DINNER * 2;    // 33.5 MB (y in-place)
    ushort_t* xdbl  = (ushort_t*)p; p += (size_t)NTOK * XDBLN * 2;     //  1.2 MB
    ushort_t* w_inT  = (ushort_t*)p; p += (size_t)2 * 2 * DINNER * DMODEL * 2;  // 16.8 MB
    ushort_t* w_xpT  = (ushort_t*)p; p += (size_t)2 * 128 * DINNER * 2;         //  1.0 MB
    ushort_t* w_dtT  = (ushort_t*)p; p += (size_t)2 * DINNER * DTRANK * 2;      //  0.5 MB
    ushort_t* w_outT = (ushort_t*)p; p += (size_t)2 * DMODEL * DINNER * 2;      //  8.4 MB
    const size_t need = (size_t)(p - (char*)d_ws);
    if (ws_size < need) return;  // clean diagnostic failure instead of page fault
    ushort_t* delta = xraw;                 // xraw dead after conv
    float* xp_part = (float*)xn;            // 16.77 MB = 4*NTOK*128*4 exactly
    float* hf   = (float*)xn;               // 8 MB  (after xp_reduce consumed partials)
    float* Ssum = hf + (size_t)NB * NCHUNK * NSTATE * DINNER;  // 2 MB

    // ---- weight prep ----
    for (int i = 0; i < 2; ++i) {
        transpose_w<<<dim3(DMODEL / 32, (2 * DINNER) / 32), 256, 0, stream>>>(
            in_proj + (size_t)i * DMODEL * 2 * DINNER,
            w_inT + (size_t)i * 2 * DINNER * DMODEL, DMODEL, 2 * DINNER, 2 * DINNER);
        transpose_w<<<dim3(DINNER / 32, 128 / 32), 256, 0, stream>>>(
            x_proj + (size_t)i * DINNER * XDBLN,
            w_xpT + (size_t)i * 128 * DINNER, DINNER, XDBLN, 128);
        transpose_w<<<dim3(DTRANK / 32, DINNER / 32), 256, 0, stream>>>(
            dt_w + (size_t)i * DTRANK * DINNER,
            w_dtT + (size_t)i * DINNER * DTRANK, DTRANK, DINNER, DINNER);
        transpose_w<<<dim3(DINNER / 32, DMODEL / 32), 256, 0, stream>>>(
            out_proj + (size_t)i * DINNER * DMODEL,
            w_outT + (size_t)i * DMODEL * DINNER, DINNER, DMODEL, DMODEL);
    }

    for (int i = 0; i < 2; ++i) {
        const float* x_in = (i == 0) ? x : x_cur;
        rmsnorm_kernel<true><<<NTOK, 256, 0, stream>>>(x_in, norm_w + (size_t)i * DMODEL, xn);
        // xraw / res = xn @ in_proj halves  (M=8192, N=2048, K=1024)
        gemm_mfma<true, false, false, false><<<dim3(DINNER / 128, NTOK / 128), 256, 0, stream>>>(
            xn, w_inT + (size_t)i * 2 * DINNER * DMODEL, xraw,
            nullptr, nullptr, DINNER, DMODEL, DMODEL, DMODEL, DINNER);
        gemm_mfma<true, false, false, false><<<dim3(DINNER / 128, NTOK / 128), 256, 0, stream>>>(
            xn, w_inT + (size_t)i * 2 * DINNER * DMODEL + (size_t)DINNER * DMODEL, res,
            nullptr, nullptr, DINNER, DMODEL, DMODEL, DMODEL, DINNER);
        conv_silu_kernel<<<(NTOK * DINNER) / 256, 256, 0, stream>>>(
            xraw, conv_w + (size_t)i * DINNER * 4, conv_b + (size_t)i * DINNER, xi);
        // xdbl = xi @ x_proj : split-K x4 into f32 partials (xn region), then reduce.
        for (int ks = 0; ks < 4; ++ks) {
            gemm_mfma<false, false, false, false><<<dim3(1, NTOK / 128), 256, 0, stream>>>(
                xi + (size_t)ks * 512,
                w_xpT + (size_t)i * 128 * DINNER + (size_t)ks * 512,
                xp_part + (size_t)ks * NTOK * 128,
                nullptr, nullptr, 128, 512, DINNER, DINNER, 128);
        }
        xp_reduce<<<NTOK, 128, 0, stream>>>(xp_part, xdbl);
        // delta = softplus(xdbl[:, :64] @ dt_w + dt_b)
        gemm_mfma<true, true, false, false><<<dim3(DINNER / 128, NTOK / 128), 256, 0, stream>>>(
            xdbl, w_dtT + (size_t)i * DINNER * DTRANK, delta,
            dt_b + (size_t)i * DINNER, nullptr, DINNER, DTRANK, XDBLN, DTRANK, DINNER);
        // selective scan
        {
            dim3 g(DINNER / 512, NCHUNK, NB);
            scan_phase1<<<g, 256, 0, stream>>>(
                delta, xi, xdbl, A_log + (size_t)i * DINNER * NSTATE, hf, Ssum);
            scan_phase2<<<(NB * NSTATE * DINNER) / 256, 256, 0, stream>>>(
                hf, Ssum, A_log + (size_t)i * DINNER * NSTATE);
            scan_phase3<<<g, 256, 0, stream>>>(
                delta, xi, xdbl, res,
                A_log + (size_t)i * DINNER * NSTATE, D_skip + (size_t)i * DINNER,
                hf, xi);
        }
        // x_cur = y @ out_proj + x_in   (f32 out, resid fused)
        gemm_mfma<false, false, true, false><<<dim3(DMODEL / 128, NTOK / 128), 256, 0, stream>>>(
            xi, w_outT + (size_t)i * DMODEL * DINNER, x_cur,
            nullptr, x_in, DMODEL, DINNER, DINNER, DINNER, DMODEL);
    }
    rmsnorm_kernel<false><<<NTOK, 256, 0, stream>>>(x_cur, norm_f_w, out);
}

// Round 6
// 862.859 us; speedup vs baseline: 13.5102x; 1.0784x over previous
//
#include <hip/hip_runtime.h>
#include <stdint.h>

#define DMODEL 1024
#define DINNER 2048
#define NSTATE 4
#define DTRANK 64
#define XDBLN  72
#define SEQL   4096
#define NB     2
#define NTOK   (NB * SEQL)
#define CHUNK  32
#define NCHUNK (SEQL / CHUNK)   // 128

typedef unsigned short ushort_t;
typedef __attribute__((ext_vector_type(8))) __bf16 bf16x8;
typedef __attribute__((ext_vector_type(4))) float f32x4;

__device__ __forceinline__ float bf2f(ushort_t h) {
    return __uint_as_float(((unsigned int)h) << 16);
}
__device__ __forceinline__ ushort_t f2bf(float f) {
    unsigned int u = __float_as_uint(f);
    u += 0x7fffu + ((u >> 16) & 1u);   // round-to-nearest-even
    return (ushort_t)(u >> 16);
}
__device__ __forceinline__ float lo16(unsigned int x) { return __uint_as_float(x << 16); }
__device__ __forceinline__ float hi16(unsigned int x) { return __uint_as_float(x & 0xffff0000u); }

// global -> LDS direct copy, 16 B per lane; lds base must be wave-uniform.
__device__ __forceinline__ void gload_lds16(const void* g, void* lds) {
    __builtin_amdgcn_global_load_lds(
        (const __attribute__((address_space(1))) unsigned int*)(uintptr_t)g,
        (__attribute__((address_space(3))) unsigned int*)(uintptr_t)lds,
        16, 0, 0);
}

// ---------------- RMSNorm: one block per token ----------------
template <bool OUT_BF16>
__global__ __launch_bounds__(256) void rmsnorm_kernel(
    const float* __restrict__ in, const float* __restrict__ w,
    void* __restrict__ outv)
{
    const int t = blockIdx.x;
    const int tid = threadIdx.x;
    const float4 v = reinterpret_cast<const float4*>(in + (size_t)t * DMODEL)[tid];
    float ss = v.x * v.x + v.y * v.y + v.z * v.z + v.w * v.w;
#pragma unroll
    for (int o = 32; o > 0; o >>= 1) ss += __shfl_xor(ss, o, 64);
    __shared__ float red[4];
    if ((tid & 63) == 0) red[tid >> 6] = ss;
    __syncthreads();
    const float total = red[0] + red[1] + red[2] + red[3];
    const float scale = rsqrtf(total * (1.0f / DMODEL) + 1e-5f);
    const float4 wv = reinterpret_cast<const float4*>(w)[tid];
    const float o0 = v.x * scale * wv.x;
    const float o1 = v.y * scale * wv.y;
    const float o2 = v.z * scale * wv.z;
    const float o3 = v.w * scale * wv.w;
    if (OUT_BF16) {
        ushort4 o;
        o.x = f2bf(o0); o.y = f2bf(o1); o.z = f2bf(o2); o.w = f2bf(o3);
        reinterpret_cast<ushort4*>((ushort_t*)outv + (size_t)t * DMODEL)[tid] = o;
    } else {
        float4 o; o.x = o0; o.y = o1; o.z = o2; o.w = o3;
        reinterpret_cast<float4*>((float*)outv + (size_t)t * DMODEL)[tid] = o;
    }
}

// ---------------- Weight prep: W[K][N] f32 -> Wt[Npad][K] bf16, batched over layers ----------------
__global__ __launch_bounds__(256) void transpose_w(
    const float* __restrict__ in, ushort_t* __restrict__ out,
    int K, int N, int Npad, size_t in_lstride, size_t out_lstride)
{
    in  += (size_t)blockIdx.z * in_lstride;
    out += (size_t)blockIdx.z * out_lstride;
    __shared__ float t[32][33];
    const int k0 = blockIdx.x * 32, n0 = blockIdx.y * 32;
    const int tx = threadIdx.x & 31, ty = threadIdx.x >> 5;  // 32 x 8
#pragma unroll
    for (int i = 0; i < 32; i += 8) {
        const int k = k0 + ty + i, n = n0 + tx;
        t[ty + i][tx] = (n < N) ? in[(size_t)k * N + n] : 0.f;
    }
    __syncthreads();
#pragma unroll
    for (int i = 0; i < 32; i += 8) {
        const int n = n0 + ty + i, k = k0 + tx;
        if (n < Npad) out[(size_t)n * K + k] = f2bf(t[tx][ty + i]);
    }
}

// ---------------- MFMA GEMM: C[M][N] = A(bf16,[M][lda]) @ Bt(bf16,[N][ldb])^T ----------------
// m97 structure: 128x128 tile, BK=32, 4 waves (2x2 of 64x64), global_load_lds width 16,
// XCD-aware bijective block swizzle (all grids have nwg % 8 == 0).
// SPLITK: blockIdx.z selects a 512-wide K-slice, partials to Cv + z*NTOK*128 (f32).
// SPLITOUT: columns >= DINNER go to Cv2 (compact ldc).
template <bool OUT_BF16, bool SOFTPLUS, bool RESID, bool NGUARD, bool SPLITK, bool SPLITOUT>
__global__ __launch_bounds__(256) void gemm_mfma(
    const ushort_t* __restrict__ A, const ushort_t* __restrict__ Bt,
    void* __restrict__ Cv, void* __restrict__ Cv2,
    const float* __restrict__ bias, const float* __restrict__ resid,
    int N, int K, int lda, int ldb, int ldc)
{
    __shared__ alignas(16) ushort_t As[128 * 32];
    __shared__ alignas(16) ushort_t Bs[128 * 32];
    const int tid = threadIdx.x;
    const int wv = tid >> 6, ln = tid & 63;
    const int wr = wv >> 1, wc = wv & 1;
    // XCD swizzle (bijective: nwg % 8 == 0 for all call sites)
    const int gx = gridDim.x;
    const int nwg = gx * gridDim.y;
    int wg = blockIdx.y * gx + blockIdx.x;
    wg = (wg & 7) * (nwg >> 3) + (wg >> 3);
    const int row0 = (wg / gx) * 128, col0 = (wg % gx) * 128;

    if constexpr (SPLITK) {
        const int z = blockIdx.z;
        A  += (size_t)z * 512;
        Bt += (size_t)z * 512;
        Cv = (void*)((float*)Cv + (size_t)z * NTOK * 128);
    }

    const int srow = ln >> 2;          // staging row within 16-row chunk
    const int ske  = (ln & 3) * 8;     // staging k-element offset
    const int fr = ln & 15, fq = ln >> 4;

    f32x4 acc[4][4] = {};

    for (int k0 = 0; k0 < K; k0 += 32) {
#pragma unroll
        for (int i = 0; i < 2; ++i) {
            const int chunk = wv * 2 + i;            // 0..7, wave-uniform
            const int r = chunk * 16 + srow;         // 0..127
            gload_lds16(A  + (size_t)(row0 + r) * lda + k0 + ske, (char*)As + chunk * 1024);
            gload_lds16(Bt + (size_t)(col0 + r) * ldb + k0 + ske, (char*)Bs + chunk * 1024);
        }
        asm volatile("s_waitcnt vmcnt(0)" ::: "memory");
        __syncthreads();
        bf16x8 af[4], bf[4];
#pragma unroll
        for (int mi = 0; mi < 4; ++mi)
            af[mi] = *(const bf16x8*)(As + (wr * 64 + mi * 16 + fr) * 32 + fq * 8);
#pragma unroll
        for (int ni = 0; ni < 4; ++ni)
            bf[ni] = *(const bf16x8*)(Bs + (wc * 64 + ni * 16 + fr) * 32 + fq * 8);
#pragma unroll
        for (int mi = 0; mi < 4; ++mi)
#pragma unroll
            for (int ni = 0; ni < 4; ++ni)
                acc[mi][ni] = __builtin_amdgcn_mfma_f32_16x16x32_bf16(
                    af[mi], bf[ni], acc[mi][ni], 0, 0, 0);
        __syncthreads();
    }

    // Output column base (SPLITOUT: route upper half to Cv2, block-uniform).
    int ccol0 = col0;
    if constexpr (SPLITOUT) {
        if (col0 >= DINNER) { Cv = Cv2; ccol0 = col0 - DINNER; }
    }

#pragma unroll
    for (int mi = 0; mi < 4; ++mi) {
#pragma unroll
        for (int ni = 0; ni < 4; ++ni) {
            const int c = ccol0 + wc * 64 + ni * 16 + fr;
            if (NGUARD && c >= N) continue;
            const float b = SOFTPLUS ? bias[c] : 0.f;
#pragma unroll
            for (int r = 0; r < 4; ++r) {
                const int rr = row0 + wr * 64 + mi * 16 + fq * 4 + r;
                float v = acc[mi][ni][r];
                if (SOFTPLUS) {
                    v += b;
                    v = fmaxf(v, 0.f) + log1pf(expf(-fabsf(v)));
                }
                if (RESID) v += resid[(size_t)rr * ldc + c];
                if (OUT_BF16) ((ushort_t*)Cv)[(size_t)rr * ldc + c] = f2bf(v);
                else          ((float*)Cv)[(size_t)rr * ldc + c]   = v;
            }
        }
    }
}

// ---------------- x_proj split-K reduce: xdbl = f2bf(sum of 4 partials) ----------------
__global__ __launch_bounds__(128) void xp_reduce(
    const float* __restrict__ part, ushort_t* __restrict__ xdbl)
{
    const int t = blockIdx.x;          // token
    const int j = threadIdx.x;         // 0..127
    if (j >= XDBLN) return;
    const size_t o = (size_t)t * 128 + j;
    const size_t stride = (size_t)NTOK * 128;
    const float s = part[o] + part[o + stride] + part[o + 2 * stride] + part[o + 3 * stride];
    xdbl[(size_t)t * XDBLN + j] = f2bf(s);
}

// ---------------- Causal depthwise conv (K=4) + bias + SiLU, 8 channels/thread ----------------
__device__ __forceinline__ void unpack8(const uint4 v, float* a) {
    a[0] = lo16(v.x); a[1] = hi16(v.x);
    a[2] = lo16(v.y); a[3] = hi16(v.y);
    a[4] = lo16(v.z); a[5] = hi16(v.z);
    a[6] = lo16(v.w); a[7] = hi16(v.w);
}

__global__ __launch_bounds__(256) void conv_silu_kernel(
    const ushort_t* __restrict__ xr, const float* __restrict__ w,
    const float* __restrict__ bcv, ushort_t* __restrict__ xi)
{
    const int idx = blockIdx.x * 256 + threadIdx.x;  // NTOK*DINNER/8
    const int cg = idx & (DINNER / 8 - 1);
    const int t  = idx >> 8;
    const int l  = t & (SEQL - 1);
    const int c0 = cg * 8;
    const size_t base = (size_t)t * DINNER + c0;
    const uint4 zz = make_uint4(0, 0, 0, 0);
    const uint4 x3 = *reinterpret_cast<const uint4*>(xr + base);
    const uint4 x2 = (l >= 1) ? *reinterpret_cast<const uint4*>(xr + base - DINNER) : zz;
    const uint4 x1 = (l >= 2) ? *reinterpret_cast<const uint4*>(xr + base - 2 * DINNER) : zz;
    const uint4 x0 = (l >= 3) ? *reinterpret_cast<const uint4*>(xr + base - 3 * DINNER) : zz;
    float a0[8], a1[8], a2[8], a3[8];
    unpack8(x0, a0); unpack8(x1, a1); unpack8(x2, a2); unpack8(x3, a3);
    ushort_t o[8];
#pragma unroll
    for (int j = 0; j < 8; ++j) {
        const float4 wj = *reinterpret_cast<const float4*>(w + (size_t)(c0 + j) * 4);
        float s = bcv[c0 + j] + wj.x * a0[j] + wj.y * a1[j] + wj.z * a2[j] + wj.w * a3[j];
        s = s / (1.0f + expf(-s));
        o[j] = f2bf(s);
    }
    uint4 ov;
    ov.x = (unsigned int)o[0] | ((unsigned int)o[1] << 16);
    ov.y = (unsigned int)o[2] | ((unsigned int)o[3] << 16);
    ov.z = (unsigned int)o[4] | ((unsigned int)o[5] << 16);
    ov.w = (unsigned int)o[6] | ((unsigned int)o[7] << 16);
    *reinterpret_cast<uint4*>(xi + base) = ov;
}

// ---------------- Chunked selective scan (CHUNK=32, 4 d-channels per thread) ----------------
__global__ __launch_bounds__(256) void scan_phase1(
    const ushort_t* __restrict__ delta, const ushort_t* __restrict__ u_in,
    const ushort_t* __restrict__ xdbl, const float* __restrict__ A_log,
    float* __restrict__ hf,    // [B][NCHUNK][NSTATE][DINNER]
    float* __restrict__ Ssum)  // [B][NCHUNK][DINNER]
{
    const int d0 = (blockIdx.x * 256 + threadIdx.x) * 4;
    const int c = blockIdx.y;
    const int b = blockIdx.z;
    float An[4][NSTATE];
#pragma unroll
    for (int j = 0; j < 4; ++j) {
        const float4 al = *reinterpret_cast<const float4*>(A_log + (size_t)(d0 + j) * NSTATE);
        An[j][0] = -expf(al.x); An[j][1] = -expf(al.y);
        An[j][2] = -expf(al.z); An[j][3] = -expf(al.w);
    }
    float h[4][NSTATE] = {};
    float S[4] = {};
    size_t idx = ((size_t)b * SEQL + (size_t)c * CHUNK) * DINNER + d0;
    size_t idx_bc = ((size_t)b * SEQL + (size_t)c * CHUNK) * XDBLN + DTRANK;
    for (int l = 0; l < CHUNK; ++l) {
        const uint2 dv2 = *reinterpret_cast<const uint2*>(delta + idx);
        const uint2 u2  = *reinterpret_cast<const uint2*>(u_in + idx);
        const uint4 bc  = *reinterpret_cast<const uint4*>(&xdbl[idx_bc]);
        const float dv[4] = { lo16(dv2.x), hi16(dv2.x), lo16(dv2.y), hi16(dv2.y) };
        const float uu[4] = { lo16(u2.x),  hi16(u2.x),  lo16(u2.y),  hi16(u2.y)  };
        const float Bv[NSTATE] = { lo16(bc.x), hi16(bc.x), lo16(bc.y), hi16(bc.y) };
#pragma unroll
        for (int j = 0; j < 4; ++j) {
            S[j] += dv[j];
            const float dvu = dv[j] * uu[j];
#pragma unroll
            for (int n = 0; n < NSTATE; ++n)
                h[j][n] = expf(dv[j] * An[j][n]) * h[j][n] + dvu * Bv[n];
        }
        idx += DINNER;
        idx_bc += XDBLN;
    }
    const size_t o = (((size_t)b * NCHUNK + c) * NSTATE) * DINNER + d0;
#pragma unroll
    for (int n = 0; n < NSTATE; ++n) {
        float4 v; v.x = h[0][n]; v.y = h[1][n]; v.z = h[2][n]; v.w = h[3][n];
        *reinterpret_cast<float4*>(hf + o + (size_t)n * DINNER) = v;
    }
    float4 sv; sv.x = S[0]; sv.y = S[1]; sv.z = S[2]; sv.w = S[3];
    *reinterpret_cast<float4*>(Ssum + ((size_t)b * NCHUNK + c) * DINNER + d0) = sv;
}

// Phase 2: in-place convert chunk-local finals -> incoming prefixes.
__global__ __launch_bounds__(256) void scan_phase2(
    float* __restrict__ hf, const float* __restrict__ Ssum,
    const float* __restrict__ A_log)
{
    const int gid = blockIdx.x * 256 + threadIdx.x;  // B*NSTATE*DINNER = 16384
    const int d = gid & (DINNER - 1);
    const int n = (gid >> 11) & 3;
    const int b = gid >> 13;
    const float An = -expf(A_log[d * NSTATE + n]);
    float hin = 0.f;
    for (int c = 0; c < NCHUNK; ++c) {
        const size_t oh = (((size_t)b * NCHUNK + c) * NSTATE + n) * DINNER + d;
        const float hl = hf[oh];
        const float Sc = Ssum[((size_t)b * NCHUNK + c) * DINNER + d];
        hf[oh] = hin;
        hin = hl + expf(An * Sc) * hin;
    }
}

// Phase 3: load h_in, run chunk recurrence, emit y fused with D-skip and *silu(res).
__global__ __launch_bounds__(256) void scan_phase3(
    const ushort_t* __restrict__ delta, const ushort_t* __restrict__ u_in,
    const ushort_t* __restrict__ xdbl, const ushort_t* __restrict__ res_in,
    const float* __restrict__ A_log, const float* __restrict__ D_skip,
    const float* __restrict__ hf, ushort_t* __restrict__ y_out)
{
    const int d0 = (blockIdx.x * 256 + threadIdx.x) * 4;
    const int c = blockIdx.y;
    const int b = blockIdx.z;
    float An[4][NSTATE];
#pragma unroll
    for (int j = 0; j < 4; ++j) {
        const float4 al = *reinterpret_cast<const float4*>(A_log + (size_t)(d0 + j) * NSTATE);
        An[j][0] = -expf(al.x); An[j][1] = -expf(al.y);
        An[j][2] = -expf(al.z); An[j][3] = -expf(al.w);
    }
    const float4 dk4 = *reinterpret_cast<const float4*>(D_skip + d0);
    const float Dk[4] = { dk4.x, dk4.y, dk4.z, dk4.w };
    float h[4][NSTATE];
    const size_t o = (((size_t)b * NCHUNK + c) * NSTATE) * DINNER + d0;
#pragma unroll
    for (int n = 0; n < NSTATE; ++n) {
        const float4 v = *reinterpret_cast<const float4*>(hf + o + (size_t)n * DINNER);
        h[0][n] = v.x; h[1][n] = v.y; h[2][n] = v.z; h[3][n] = v.w;
    }
    size_t idx = ((size_t)b * SEQL + (size_t)c * CHUNK) * DINNER + d0;
    size_t idx_bc = ((size_t)b * SEQL + (size_t)c * CHUNK) * XDBLN + DTRANK;
    for (int l = 0; l < CHUNK; ++l) {
        const uint2 dv2 = *reinterpret_cast<const uint2*>(delta + idx);
        const uint2 u2  = *reinterpret_cast<const uint2*>(u_in + idx);
        const uint2 r2  = *reinterpret_cast<const uint2*>(res_in + idx);
        const uint4 bc  = *reinterpret_cast<const uint4*>(&xdbl[idx_bc]);
        const float dv[4] = { lo16(dv2.x), hi16(dv2.x), lo16(dv2.y), hi16(dv2.y) };
        const float uu[4] = { lo16(u2.x),  hi16(u2.x),  lo16(u2.y),  hi16(u2.y)  };
        const float rr[4] = { lo16(r2.x),  hi16(r2.x),  lo16(r2.y),  hi16(r2.y)  };
        const float Bv[NSTATE] = { lo16(bc.x), hi16(bc.x), lo16(bc.y), hi16(bc.y) };
        const float Cw[NSTATE] = { lo16(bc.z), hi16(bc.z), lo16(bc.w), hi16(bc.w) };
        ushort_t yo[4];
#pragma unroll
        for (int j = 0; j < 4; ++j) {
            const float dvu = dv[j] * uu[j];
            float y = 0.f;
#pragma unroll
            for (int n = 0; n < NSTATE; ++n) {
                h[j][n] = expf(dv[j] * An[j][n]) * h[j][n] + dvu * Bv[n];
                y += h[j][n] * Cw[n];
            }
            const float sil = rr[j] / (1.0f + expf(-rr[j]));
            yo[j] = f2bf((y + uu[j] * Dk[j]) * sil);
        }
        uint2 ov;
        ov.x = (unsigned int)yo[0] | ((unsigned int)yo[1] << 16);
        ov.y = (unsigned int)yo[2] | ((unsigned int)yo[3] << 16);
        *reinterpret_cast<uint2*>(y_out + idx) = ov;
        idx += DINNER;
        idx_bc += XDBLN;
    }
}

// ---------------- Orchestration ----------------
extern "C" void kernel_launch(void* const* d_in, const int* in_sizes, int n_in,
                              void* d_out, int out_size, void* d_ws, size_t ws_size,
                              hipStream_t stream)
{
    const float* x        = (const float*)d_in[0];
    const float* in_proj  = (const float*)d_in[1];
    const float* conv_w   = (const float*)d_in[2];
    const float* conv_b   = (const float*)d_in[3];
    const float* x_proj   = (const float*)d_in[4];
    const float* dt_w     = (const float*)d_in[5];
    const float* dt_b     = (const float*)d_in[6];
    const float* A_log    = (const float*)d_in[7];
    const float* D_skip   = (const float*)d_in[8];
    const float* out_proj = (const float*)d_in[9];
    const float* norm_w   = (const float*)d_in[10];
    const float* norm_f_w = (const float*)d_in[11];
    float* out = (float*)d_out;

    // Workspace layout: ~178.8 MB total (all chunks 16B-aligned).
    char* p = (char*)d_ws;
    float*    x_cur = (float*)p;    p += (size_t)NTOK * DMODEL * 4;    // 33.5 MB
    ushort_t* xn    = (ushort_t*)p; p += (size_t)NTOK * DMODEL * 2;    // 16.8 MB (xp partials / hf+Ssum reuse)
    ushort_t* xraw  = (ushort_t*)p; p += (size_t)NTOK * DINNER * 2;    // 33.5 MB (delta reuses)
    ushort_t* res   = (ushort_t*)p; p += (size_t)NTOK * DINNER * 2;    // 33.5 MB
    ushort_t* xi    = (ushort_t*)p; p += (size_t)NTOK * DINNER * 2;    // 33.5 MB (y in-place)
    ushort_t* xdbl  = (ushort_t*)p; p += (size_t)NTOK * XDBLN * 2;     //  1.2 MB
    ushort_t* w_inT  = (ushort_t*)p; p += (size_t)2 * 2 * DINNER * DMODEL * 2;  // 16.8 MB
    ushort_t* w_xpT  = (ushort_t*)p; p += (size_t)2 * 128 * DINNER * 2;         //  1.0 MB
    ushort_t* w_dtT  = (ushort_t*)p; p += (size_t)2 * DINNER * DTRANK * 2;      //  0.5 MB
    ushort_t* w_outT = (ushort_t*)p; p += (size_t)2 * DMODEL * DINNER * 2;      //  8.4 MB
    const size_t need = (size_t)(p - (char*)d_ws);
    if (ws_size < need) return;  // clean diagnostic failure instead of page fault
    ushort_t* delta = xraw;                 // xraw dead after conv
    float* xp_part = (float*)xn;            // 16.77 MB = 4*NTOK*128*4 exactly
    float* hf   = (float*)xn;               // 8 MB (after xp_reduce consumed partials)
    float* Ssum = hf + (size_t)NB * NCHUNK * NSTATE * DINNER;  // 2 MB

    // ---- weight prep (batched over both layers via grid.z) ----
    transpose_w<<<dim3(DMODEL / 32, (2 * DINNER) / 32, 2), 256, 0, stream>>>(
        in_proj, w_inT, DMODEL, 2 * DINNER, 2 * DINNER,
        (size_t)DMODEL * 2 * DINNER, (size_t)2 * DINNER * DMODEL);
    transpose_w<<<dim3(DINNER / 32, 128 / 32, 2), 256, 0, stream>>>(
        x_proj, w_xpT, DINNER, XDBLN, 128,
        (size_t)DINNER * XDBLN, (size_t)128 * DINNER);
    transpose_w<<<dim3(DTRANK / 32, DINNER / 32, 2), 256, 0, stream>>>(
        dt_w, w_dtT, DTRANK, DINNER, DINNER,
        (size_t)DTRANK * DINNER, (size_t)DINNER * DTRANK);
    transpose_w<<<dim3(DINNER / 32, DMODEL / 32, 2), 256, 0, stream>>>(
        out_proj, w_outT, DINNER, DMODEL, DMODEL,
        (size_t)DINNER * DMODEL, (size_t)DMODEL * DINNER);

    for (int i = 0; i < 2; ++i) {
        const float* x_in = (i == 0) ? x : x_cur;
        rmsnorm_kernel<true><<<NTOK, 256, 0, stream>>>(x_in, norm_w + (size_t)i * DMODEL, xn);
        // Fused in_proj: N=4096, split-output (cols<2048 -> xraw, else -> res).
        gemm_mfma<true, false, false, false, false, true>
            <<<dim3((2 * DINNER) / 128, NTOK / 128), 256, 0, stream>>>(
            xn, w_inT + (size_t)i * 2 * DINNER * DMODEL, xraw, res,
            nullptr, nullptr, 2 * DINNER, DMODEL, DMODEL, DMODEL, DINNER);
        conv_silu_kernel<<<(NTOK * DINNER / 8) / 256, 256, 0, stream>>>(
            xraw, conv_w + (size_t)i * DINNER * 4, conv_b + (size_t)i * DINNER, xi);
        // xdbl = xi @ x_proj : split-K x4 in one dispatch (grid.z), f32 partials, then reduce.
        gemm_mfma<false, false, false, false, true, false>
            <<<dim3(1, NTOK / 128, 4), 256, 0, stream>>>(
            xi, w_xpT + (size_t)i * 128 * DINNER, xp_part, nullptr,
            nullptr, nullptr, 128, 512, DINNER, DINNER, 128);
        xp_reduce<<<NTOK, 128, 0, stream>>>(xp_part, xdbl);
        // delta = softplus(xdbl[:, :64] @ dt_w + dt_b)
        gemm_mfma<true, true, false, false, false, false>
            <<<dim3(DINNER / 128, NTOK / 128), 256, 0, stream>>>(
            xdbl, w_dtT + (size_t)i * DINNER * DTRANK, delta, nullptr,
            dt_b + (size_t)i * DINNER, nullptr, DINNER, DTRANK, XDBLN, DTRANK, DINNER);
        // selective scan
        {
            dim3 g(DINNER / 1024, NCHUNK, NB);
            scan_phase1<<<g, 256, 0, stream>>>(
                delta, xi, xdbl, A_log + (size_t)i * DINNER * NSTATE, hf, Ssum);
            scan_phase2<<<(NB * NSTATE * DINNER) / 256, 256, 0, stream>>>(
                hf, Ssum, A_log + (size_t)i * DINNER * NSTATE);
            scan_phase3<<<g, 256, 0, stream>>>(
                delta, xi, xdbl, res,
                A_log + (size_t)i * DINNER * NSTATE, D_skip + (size_t)i * DINNER,
                hf, xi);
        }
        // x_cur = y @ out_proj + x_in   (f32 out, resid fused)
        gemm_mfma<false, false, true, false, false, false>
            <<<dim3(DMODEL / 128, NTOK / 128), 256, 0, stream>>>(
            xi, w_outT + (size_t)i * DMODEL * DINNER, x_cur, nullptr,
            nullptr, x_in, DMODEL, DINNER, DINNER, DINNER, DMODEL);
    }
    rmsnorm_kernel<false><<<NTOK, 256, 0, stream>>>(x_cur, norm_f_w, out);
}

// Round 7
// 686.889 us; speedup vs baseline: 16.9714x; 1.2562x over previous
//
#include <hip/hip_runtime.h>
#include <stdint.h>

#define DMODEL 1024
#define DINNER 2048
#define NSTATE 4
#define DTRANK 64
#define XDBLN  72
#define SEQL   4096
#define NB     2
#define NTOK   (NB * SEQL)
#define CHUNK  32
#define NCHUNK (SEQL / CHUNK)   // 128

typedef unsigned short ushort_t;
typedef __attribute__((ext_vector_type(8))) __bf16 bf16x8;
typedef __attribute__((ext_vector_type(4))) float f32x4;

__device__ __forceinline__ float bf2f(ushort_t h) {
    return __uint_as_float(((unsigned int)h) << 16);
}
__device__ __forceinline__ ushort_t f2bf(float f) {
    unsigned int u = __float_as_uint(f);
    u += 0x7fffu + ((u >> 16) & 1u);   // round-to-nearest-even
    return (ushort_t)(u >> 16);
}
__device__ __forceinline__ float lo16(unsigned int x) { return __uint_as_float(x << 16); }
__device__ __forceinline__ float hi16(unsigned int x) { return __uint_as_float(x & 0xffff0000u); }
__device__ __forceinline__ float fexp(float x) { return __expf(x); }
__device__ __forceinline__ float frcp(float x) { return __builtin_amdgcn_rcpf(x); }

// global -> LDS direct copy, 16 B per lane; lds base must be wave-uniform.
__device__ __forceinline__ void gload_lds16(const void* g, void* lds) {
    __builtin_amdgcn_global_load_lds(
        (const __attribute__((address_space(1))) unsigned int*)(uintptr_t)g,
        (__attribute__((address_space(3))) unsigned int*)(uintptr_t)lds,
        16, 0, 0);
}

// ---------------- RMSNorm: one block per token ----------------
template <bool OUT_BF16>
__global__ __launch_bounds__(256) void rmsnorm_kernel(
    const float* __restrict__ in, const float* __restrict__ w,
    void* __restrict__ outv)
{
    const int t = blockIdx.x;
    const int tid = threadIdx.x;
    const float4 v = reinterpret_cast<const float4*>(in + (size_t)t * DMODEL)[tid];
    float ss = v.x * v.x + v.y * v.y + v.z * v.z + v.w * v.w;
#pragma unroll
    for (int o = 32; o > 0; o >>= 1) ss += __shfl_xor(ss, o, 64);
    __shared__ float red[4];
    if ((tid & 63) == 0) red[tid >> 6] = ss;
    __syncthreads();
    const float total = red[0] + red[1] + red[2] + red[3];
    const float scale = rsqrtf(total * (1.0f / DMODEL) + 1e-5f);
    const float4 wv = reinterpret_cast<const float4*>(w)[tid];
    const float o0 = v.x * scale * wv.x;
    const float o1 = v.y * scale * wv.y;
    const float o2 = v.z * scale * wv.z;
    const float o3 = v.w * scale * wv.w;
    if (OUT_BF16) {
        ushort4 o;
        o.x = f2bf(o0); o.y = f2bf(o1); o.z = f2bf(o2); o.w = f2bf(o3);
        reinterpret_cast<ushort4*>((ushort_t*)outv + (size_t)t * DMODEL)[tid] = o;
    } else {
        float4 o; o.x = o0; o.y = o1; o.z = o2; o.w = o3;
        reinterpret_cast<float4*>((float*)outv + (size_t)t * DMODEL)[tid] = o;
    }
}

// ---------------- Fused weight prep: all 4 weight transposes in ONE launch ----------------
// W[K][N] f32 -> Wt[Npad][K] bf16 (pad rows zeroed).  grid.z = layer.
#define TILES_IN  ((DMODEL / 32) * ((2 * DINNER) / 32))   // 4096
#define TILES_XP  ((DINNER / 32) * (128 / 32))            // 256
#define TILES_DT  ((DTRANK / 32) * (DINNER / 32))         // 128
#define TILES_OUT ((DINNER / 32) * (DMODEL / 32))         // 2048
#define TILES_ALL (TILES_IN + TILES_XP + TILES_DT + TILES_OUT)  // 6528

__global__ __launch_bounds__(256) void prep_weights(
    const float* __restrict__ in_proj, const float* __restrict__ x_proj,
    const float* __restrict__ dt_w, const float* __restrict__ out_proj,
    ushort_t* __restrict__ w_inT, ushort_t* __restrict__ w_xpT,
    ushort_t* __restrict__ w_dtT, ushort_t* __restrict__ w_outT)
{
    const int layer = blockIdx.z;
    int tb = blockIdx.x;
    const float* src; ushort_t* dst; int K, N, Npad;
    if (tb < TILES_IN) {
        src = in_proj + (size_t)layer * DMODEL * 2 * DINNER;
        dst = w_inT + (size_t)layer * 2 * DINNER * DMODEL;
        K = DMODEL; N = 2 * DINNER; Npad = 2 * DINNER;
    } else if ((tb -= TILES_IN) < TILES_XP) {
        src = x_proj + (size_t)layer * DINNER * XDBLN;
        dst = w_xpT + (size_t)layer * 128 * DINNER;
        K = DINNER; N = XDBLN; Npad = 128;
    } else if ((tb -= TILES_XP) < TILES_DT) {
        src = dt_w + (size_t)layer * DTRANK * DINNER;
        dst = w_dtT + (size_t)layer * DINNER * DTRANK;
        K = DTRANK; N = DINNER; Npad = DINNER;
    } else {
        tb -= TILES_DT;
        src = out_proj + (size_t)layer * DINNER * DMODEL;
        dst = w_outT + (size_t)layer * DMODEL * DINNER;
        K = DINNER; N = DMODEL; Npad = DMODEL;
    }
    const int ktiles = K >> 5;
    const int k0 = (tb % ktiles) * 32, n0 = (tb / ktiles) * 32;
    __shared__ float t[32][33];
    const int tx = threadIdx.x & 31, ty = threadIdx.x >> 5;  // 32 x 8
#pragma unroll
    for (int i = 0; i < 32; i += 8) {
        const int k = k0 + ty + i, n = n0 + tx;
        t[ty + i][tx] = (n < N) ? src[(size_t)k * N + n] : 0.f;
    }
    __syncthreads();
#pragma unroll
    for (int i = 0; i < 32; i += 8) {
        const int n = n0 + ty + i, k = k0 + tx;
        if (n < Npad) dst[(size_t)n * K + k] = f2bf(t[tx][ty + i]);
    }
}

// ---------------- MFMA GEMM: C[M][N] = A(bf16,[M][lda]) @ Bt(bf16,[N][ldb])^T ----------------
// 128x128 tile, BK=32, 4 waves, global_load_lds width 16, XCD-aware swizzle.
// 3-buffer LDS ring + counted vmcnt (never 0 mid-loop) + raw barriers:
// stage tile t+2 while computing tile t; vmcnt(8) leaves tiles t+1,t+2 in flight.
template <bool OUT_BF16, bool SOFTPLUS, bool RESID, bool NGUARD, bool SPLITK, bool SPLITOUT>
__global__ __launch_bounds__(256) void gemm_mfma(
    const ushort_t* __restrict__ A, const ushort_t* __restrict__ Bt,
    void* __restrict__ Cv, void* __restrict__ Cv2,
    const float* __restrict__ bias, const float* __restrict__ resid,
    int N, int K, int lda, int ldb, int ldc)
{
    __shared__ alignas(16) ushort_t As[3][128 * 32];   // 3 x 8 KB
    __shared__ alignas(16) ushort_t Bs[3][128 * 32];   // 3 x 8 KB
    const int tid = threadIdx.x;
    const int wv = tid >> 6, ln = tid & 63;
    const int wr = wv >> 1, wc = wv & 1;
    // XCD swizzle (bijective: nwg % 8 == 0 for all call sites)
    const int gx = gridDim.x;
    const int nwg = gx * gridDim.y;
    int wg = blockIdx.y * gx + blockIdx.x;
    wg = (wg & 7) * (nwg >> 3) + (wg >> 3);
    const int row0 = (wg / gx) * 128, col0 = (wg % gx) * 128;

    if constexpr (SPLITK) {
        const int z = blockIdx.z;
        A  += (size_t)z * 512;
        Bt += (size_t)z * 512;
        Cv = (void*)((float*)Cv + (size_t)z * NTOK * 128);
    }

    const int srow = ln >> 2;          // staging row within 16-row chunk
    const int ske  = (ln & 3) * 8;     // staging k-element offset
    const int fr = ln & 15, fq = ln >> 4;
    const int nt = K >> 5;

    auto stage = [&](int buf, int t) {
        const int k0 = t << 5;
#pragma unroll
        for (int i = 0; i < 2; ++i) {
            const int chunk = wv * 2 + i;            // 0..7, wave-uniform
            const int r = chunk * 16 + srow;         // 0..127
            gload_lds16(A  + (size_t)(row0 + r) * lda + k0 + ske,
                        (char*)&As[buf][0] + chunk * 1024);
            gload_lds16(Bt + (size_t)(col0 + r) * ldb + k0 + ske,
                        (char*)&Bs[buf][0] + chunk * 1024);
        }
    };

    stage(0, 0);
    if (nt > 1) stage(1, 1);

    f32x4 acc[4][4] = {};
    int cur = 0;
    for (int t = 0; t < nt; ++t) {
        if (t + 2 < nt) {
            int nb = cur + 2; if (nb >= 3) nb -= 3;
            stage(nb, t + 2);
        }
        const int rem = nt - 1 - t;
        if (rem >= 2)      asm volatile("s_waitcnt vmcnt(8)" ::: "memory");
        else if (rem == 1) asm volatile("s_waitcnt vmcnt(4)" ::: "memory");
        else               asm volatile("s_waitcnt vmcnt(0)" ::: "memory");
        asm volatile("s_barrier" ::: "memory");   // tile t fully in LDS for all waves
        const ushort_t* as = &As[cur][0];
        const ushort_t* bs = &Bs[cur][0];
        bf16x8 af[4], bfr[4];
#pragma unroll
        for (int mi = 0; mi < 4; ++mi)
            af[mi] = *(const bf16x8*)(as + (wr * 64 + mi * 16 + fr) * 32 + fq * 8);
#pragma unroll
        for (int ni = 0; ni < 4; ++ni)
            bfr[ni] = *(const bf16x8*)(bs + (wc * 64 + ni * 16 + fr) * 32 + fq * 8);
#pragma unroll
        for (int mi = 0; mi < 4; ++mi)
#pragma unroll
            for (int ni = 0; ni < 4; ++ni)
                acc[mi][ni] = __builtin_amdgcn_mfma_f32_16x16x32_bf16(
                    af[mi], bfr[ni], acc[mi][ni], 0, 0, 0);
        asm volatile("s_barrier" ::: "memory");   // frees buf cur for stage t+3
        cur = (cur + 1 == 3) ? 0 : cur + 1;
    }

    // Output column base (SPLITOUT: route upper half to Cv2, block-uniform).
    int ccol0 = col0;
    if constexpr (SPLITOUT) {
        if (col0 >= DINNER) { Cv = Cv2; ccol0 = col0 - DINNER; }
    }

#pragma unroll
    for (int mi = 0; mi < 4; ++mi) {
#pragma unroll
        for (int ni = 0; ni < 4; ++ni) {
            const int c = ccol0 + wc * 64 + ni * 16 + fr;
            if (NGUARD && c >= N) continue;
            const float b = SOFTPLUS ? bias[c] : 0.f;
#pragma unroll
            for (int r = 0; r < 4; ++r) {
                const int rr = row0 + wr * 64 + mi * 16 + fq * 4 + r;
                float v = acc[mi][ni][r];
                if (SOFTPLUS) {
                    v += b;
                    v = fmaxf(v, 0.f) + log1pf(fexp(-fabsf(v)));
                }
                if (RESID) v += resid[(size_t)rr * ldc + c];
                if (OUT_BF16) ((ushort_t*)Cv)[(size_t)rr * ldc + c] = f2bf(v);
                else          ((float*)Cv)[(size_t)rr * ldc + c]   = v;
            }
        }
    }
}

// ---------------- x_proj split-K reduce: xdbl = f2bf(sum of 4 partials) ----------------
__global__ __launch_bounds__(128) void xp_reduce(
    const float* __restrict__ part, ushort_t* __restrict__ xdbl)
{
    const int t = blockIdx.x;          // token
    const int j = threadIdx.x;         // 0..127
    if (j >= XDBLN) return;
    const size_t o = (size_t)t * 128 + j;
    const size_t stride = (size_t)NTOK * 128;
    const float s = part[o] + part[o + stride] + part[o + 2 * stride] + part[o + 3 * stride];
    xdbl[(size_t)t * XDBLN + j] = f2bf(s);
}

// ---------------- Causal depthwise conv (K=4) + bias + SiLU, 8 channels/thread ----------------
__device__ __forceinline__ void unpack8(const uint4 v, float* a) {
    a[0] = lo16(v.x); a[1] = hi16(v.x);
    a[2] = lo16(v.y); a[3] = hi16(v.y);
    a[4] = lo16(v.z); a[5] = hi16(v.z);
    a[6] = lo16(v.w); a[7] = hi16(v.w);
}

__global__ __launch_bounds__(256) void conv_silu_kernel(
    const ushort_t* __restrict__ xr, const float* __restrict__ w,
    const float* __restrict__ bcv, ushort_t* __restrict__ xi)
{
    const int idx = blockIdx.x * 256 + threadIdx.x;  // NTOK*DINNER/8
    const int cg = idx & (DINNER / 8 - 1);
    const int t  = idx >> 8;
    const int l  = t & (SEQL - 1);
    const int c0 = cg * 8;
    const size_t base = (size_t)t * DINNER + c0;
    const uint4 zz = make_uint4(0, 0, 0, 0);
    const uint4 x3 = *reinterpret_cast<const uint4*>(xr + base);
    const uint4 x2 = (l >= 1) ? *reinterpret_cast<const uint4*>(xr + base - DINNER) : zz;
    const uint4 x1 = (l >= 2) ? *reinterpret_cast<const uint4*>(xr + base - 2 * DINNER) : zz;
    const uint4 x0 = (l >= 3) ? *reinterpret_cast<const uint4*>(xr + base - 3 * DINNER) : zz;
    float a0[8], a1[8], a2[8], a3[8];
    unpack8(x0, a0); unpack8(x1, a1); unpack8(x2, a2); unpack8(x3, a3);
    ushort_t o[8];
#pragma unroll
    for (int j = 0; j < 8; ++j) {
        const float4 wj = *reinterpret_cast<const float4*>(w + (size_t)(c0 + j) * 4);
        float s = bcv[c0 + j] + wj.x * a0[j] + wj.y * a1[j] + wj.z * a2[j] + wj.w * a3[j];
        s = s * frcp(1.0f + fexp(-s));
        o[j] = f2bf(s);
    }
    uint4 ov;
    ov.x = (unsigned int)o[0] | ((unsigned int)o[1] << 16);
    ov.y = (unsigned int)o[2] | ((unsigned int)o[3] << 16);
    ov.z = (unsigned int)o[4] | ((unsigned int)o[5] << 16);
    ov.w = (unsigned int)o[6] | ((unsigned int)o[7] << 16);
    *reinterpret_cast<uint4*>(xi + base) = ov;
}

// ---------------- Chunked selective scan (CHUNK=32, 4 d-channels per thread) ----------------
__global__ __launch_bounds__(256) void scan_phase1(
    const ushort_t* __restrict__ delta, const ushort_t* __restrict__ u_in,
    const ushort_t* __restrict__ xdbl, const float* __restrict__ A_log,
    float* __restrict__ hf,    // [B][NCHUNK][NSTATE][DINNER]
    float* __restrict__ Ssum)  // [B][NCHUNK][DINNER]
{
    const int d0 = (blockIdx.x * 256 + threadIdx.x) * 4;
    const int c = blockIdx.y;
    const int b = blockIdx.z;
    float An[4][NSTATE];
#pragma unroll
    for (int j = 0; j < 4; ++j) {
        const float4 al = *reinterpret_cast<const float4*>(A_log + (size_t)(d0 + j) * NSTATE);
        An[j][0] = -fexp(al.x); An[j][1] = -fexp(al.y);
        An[j][2] = -fexp(al.z); An[j][3] = -fexp(al.w);
    }
    float h[4][NSTATE] = {};
    float S[4] = {};
    size_t idx = ((size_t)b * SEQL + (size_t)c * CHUNK) * DINNER + d0;
    size_t idx_bc = ((size_t)b * SEQL + (size_t)c * CHUNK) * XDBLN + DTRANK;
    for (int l = 0; l < CHUNK; ++l) {
        const uint2 dv2 = *reinterpret_cast<const uint2*>(delta + idx);
        const uint2 u2  = *reinterpret_cast<const uint2*>(u_in + idx);
        const uint4 bc  = *reinterpret_cast<const uint4*>(&xdbl[idx_bc]);
        const float dv[4] = { lo16(dv2.x), hi16(dv2.x), lo16(dv2.y), hi16(dv2.y) };
        const float uu[4] = { lo16(u2.x),  hi16(u2.x),  lo16(u2.y),  hi16(u2.y)  };
        const float Bv[NSTATE] = { lo16(bc.x), hi16(bc.x), lo16(bc.y), hi16(bc.y) };
#pragma unroll
        for (int j = 0; j < 4; ++j) {
            S[j] += dv[j];
            const float dvu = dv[j] * uu[j];
#pragma unroll
            for (int n = 0; n < NSTATE; ++n)
                h[j][n] = fexp(dv[j] * An[j][n]) * h[j][n] + dvu * Bv[n];
        }
        idx += DINNER;
        idx_bc += XDBLN;
    }
    const size_t o = (((size_t)b * NCHUNK + c) * NSTATE) * DINNER + d0;
#pragma unroll
    for (int n = 0; n < NSTATE; ++n) {
        float4 v; v.x = h[0][n]; v.y = h[1][n]; v.z = h[2][n]; v.w = h[3][n];
        *reinterpret_cast<float4*>(hf + o + (size_t)n * DINNER) = v;
    }
    float4 sv; sv.x = S[0]; sv.y = S[1]; sv.z = S[2]; sv.w = S[3];
    *reinterpret_cast<float4*>(Ssum + ((size_t)b * NCHUNK + c) * DINNER + d0) = sv;
}

// Phase 2: in-place convert chunk-local finals -> incoming prefixes.
__global__ __launch_bounds__(256) void scan_phase2(
    float* __restrict__ hf, const float* __restrict__ Ssum,
    const float* __restrict__ A_log)
{
    const int gid = blockIdx.x * 256 + threadIdx.x;  // B*NSTATE*DINNER = 16384
    const int d = gid & (DINNER - 1);
    const int n = (gid >> 11) & 3;
    const int b = gid >> 13;
    const float An = -fexp(A_log[d * NSTATE + n]);
    float hin = 0.f;
    for (int c = 0; c < NCHUNK; ++c) {
        const size_t oh = (((size_t)b * NCHUNK + c) * NSTATE + n) * DINNER + d;
        const float hl = hf[oh];
        const float Sc = Ssum[((size_t)b * NCHUNK + c) * DINNER + d];
        hf[oh] = hin;
        hin = hl + fexp(An * Sc) * hin;
    }
}

// Phase 3: load h_in, run chunk recurrence, emit y fused with D-skip and *silu(res).
__global__ __launch_bounds__(256) void scan_phase3(
    const ushort_t* __restrict__ delta, const ushort_t* __restrict__ u_in,
    const ushort_t* __restrict__ xdbl, const ushort_t* __restrict__ res_in,
    const float* __restrict__ A_log, const float* __restrict__ D_skip,
    const float* __restrict__ hf, ushort_t* __restrict__ y_out)
{
    const int d0 = (blockIdx.x * 256 + threadIdx.x) * 4;
    const int c = blockIdx.y;
    const int b = blockIdx.z;
    float An[4][NSTATE];
#pragma unroll
    for (int j = 0; j < 4; ++j) {
        const float4 al = *reinterpret_cast<const float4*>(A_log + (size_t)(d0 + j) * NSTATE);
        An[j][0] = -fexp(al.x); An[j][1] = -fexp(al.y);
        An[j][2] = -fexp(al.z); An[j][3] = -fexp(al.w);
    }
    const float4 dk4 = *reinterpret_cast<const float4*>(D_skip + d0);
    const float Dk[4] = { dk4.x, dk4.y, dk4.z, dk4.w };
    float h[4][NSTATE];
    const size_t o = (((size_t)b * NCHUNK + c) * NSTATE) * DINNER + d0;
#pragma unroll
    for (int n = 0; n < NSTATE; ++n) {
        const float4 v = *reinterpret_cast<const float4*>(hf + o + (size_t)n * DINNER);
        h[0][n] = v.x; h[1][n] = v.y; h[2][n] = v.z; h[3][n] = v.w;
    }
    size_t idx = ((size_t)b * SEQL + (size_t)c * CHUNK) * DINNER + d0;
    size_t idx_bc = ((size_t)b * SEQL + (size_t)c * CHUNK) * XDBLN + DTRANK;
    for (int l = 0; l < CHUNK; ++l) {
        const uint2 dv2 = *reinterpret_cast<const uint2*>(delta + idx);
        const uint2 u2  = *reinterpret_cast<const uint2*>(u_in + idx);
        const uint2 r2  = *reinterpret_cast<const uint2*>(res_in + idx);
        const uint4 bc  = *reinterpret_cast<const uint4*>(&xdbl[idx_bc]);
        const float dv[4] = { lo16(dv2.x), hi16(dv2.x), lo16(dv2.y), hi16(dv2.y) };
        const float uu[4] = { lo16(u2.x),  hi16(u2.x),  lo16(u2.y),  hi16(u2.y)  };
        const float rr[4] = { lo16(r2.x),  hi16(r2.x),  lo16(r2.y),  hi16(r2.y)  };
        const float Bv[NSTATE] = { lo16(bc.x), hi16(bc.x), lo16(bc.y), hi16(bc.y) };
        const float Cw[NSTATE] = { lo16(bc.z), hi16(bc.z), lo16(bc.w), hi16(bc.w) };
        ushort_t yo[4];
#pragma unroll
        for (int j = 0; j < 4; ++j) {
            const float dvu = dv[j] * uu[j];
            float y = 0.f;
#pragma unroll
            for (int n = 0; n < NSTATE; ++n) {
                h[j][n] = fexp(dv[j] * An[j][n]) * h[j][n] + dvu * Bv[n];
                y += h[j][n] * Cw[n];
            }
            const float sil = rr[j] * frcp(1.0f + fexp(-rr[j]));
            yo[j] = f2bf((y + uu[j] * Dk[j]) * sil);
        }
        uint2 ov;
        ov.x = (unsigned int)yo[0] | ((unsigned int)yo[1] << 16);
        ov.y = (unsigned int)yo[2] | ((unsigned int)yo[3] << 16);
        *reinterpret_cast<uint2*>(y_out + idx) = ov;
        idx += DINNER;
        idx_bc += XDBLN;
    }
}

// ---------------- Orchestration ----------------
extern "C" void kernel_launch(void* const* d_in, const int* in_sizes, int n_in,
                              void* d_out, int out_size, void* d_ws, size_t ws_size,
                              hipStream_t stream)
{
    const float* x        = (const float*)d_in[0];
    const float* in_proj  = (const float*)d_in[1];
    const float* conv_w   = (const float*)d_in[2];
    const float* conv_b   = (const float*)d_in[3];
    const float* x_proj   = (const float*)d_in[4];
    const float* dt_w     = (const float*)d_in[5];
    const float* dt_b     = (const float*)d_in[6];
    const float* A_log    = (const float*)d_in[7];
    const float* D_skip   = (const float*)d_in[8];
    const float* out_proj = (const float*)d_in[9];
    const float* norm_w   = (const float*)d_in[10];
    const float* norm_f_w = (const float*)d_in[11];
    float* out = (float*)d_out;

    // Workspace layout: ~178.8 MB total (all chunks 16B-aligned).
    char* p = (char*)d_ws;
    float*    x_cur = (float*)p;    p += (size_t)NTOK * DMODEL * 4;    // 33.5 MB
    ushort_t* xn    = (ushort_t*)p; p += (size_t)NTOK * DMODEL * 2;    // 16.8 MB (xp partials / hf+Ssum reuse)
    ushort_t* xraw  = (ushort_t*)p; p += (size_t)NTOK * DINNER * 2;    // 33.5 MB (delta reuses)
    ushort_t* res   = (ushort_t*)p; p += (size_t)NTOK * DINNER * 2;    // 33.5 MB
    ushort_t* xi    = (ushort_t*)p; p += (size_t)NTOK * DINNER * 2;    // 33.5 MB (y in-place)
    ushort_t* xdbl  = (ushort_t*)p; p += (size_t)NTOK * XDBLN * 2;     //  1.2 MB
    ushort_t* w_inT  = (ushort_t*)p; p += (size_t)2 * 2 * DINNER * DMODEL * 2;  // 16.8 MB
    ushort_t* w_xpT  = (ushort_t*)p; p += (size_t)2 * 128 * DINNER * 2;         //  1.0 MB
    ushort_t* w_dtT  = (ushort_t*)p; p += (size_t)2 * DINNER * DTRANK * 2;      //  0.5 MB
    ushort_t* w_outT = (ushort_t*)p; p += (size_t)2 * DMODEL * DINNER * 2;      //  8.4 MB
    const size_t need = (size_t)(p - (char*)d_ws);
    if (ws_size < need) return;  // clean diagnostic failure instead of page fault
    ushort_t* delta = xraw;                 // xraw dead after conv
    float* xp_part = (float*)xn;            // 16.77 MB = 4*NTOK*128*4 exactly
    float* hf   = (float*)xn;               // 8 MB (after xp_reduce consumed partials)
    float* Ssum = hf + (size_t)NB * NCHUNK * NSTATE * DINNER;  // 2 MB

    // ---- fused weight prep (single launch, both layers) ----
    prep_weights<<<dim3(TILES_ALL, 1, 2), 256, 0, stream>>>(
        in_proj, x_proj, dt_w, out_proj, w_inT, w_xpT, w_dtT, w_outT);

    for (int i = 0; i < 2; ++i) {
        const float* x_in = (i == 0) ? x : x_cur;
        rmsnorm_kernel<true><<<NTOK, 256, 0, stream>>>(x_in, norm_w + (size_t)i * DMODEL, xn);
        // Fused in_proj: N=4096, split-output (cols<2048 -> xraw, else -> res).
        gemm_mfma<true, false, false, false, false, true>
            <<<dim3((2 * DINNER) / 128, NTOK / 128), 256, 0, stream>>>(
            xn, w_inT + (size_t)i * 2 * DINNER * DMODEL, xraw, res,
            nullptr, nullptr, 2 * DINNER, DMODEL, DMODEL, DMODEL, DINNER);
        conv_silu_kernel<<<(NTOK * DINNER / 8) / 256, 256, 0, stream>>>(
            xraw, conv_w + (size_t)i * DINNER * 4, conv_b + (size_t)i * DINNER, xi);
        // xdbl = xi @ x_proj : split-K x4 in one dispatch (grid.z), f32 partials, then reduce.
        gemm_mfma<false, false, false, false, true, false>
            <<<dim3(1, NTOK / 128, 4), 256, 0, stream>>>(
            xi, w_xpT + (size_t)i * 128 * DINNER, xp_part, nullptr,
            nullptr, nullptr, 128, 512, DINNER, DINNER, 128);
        xp_reduce<<<NTOK, 128, 0, stream>>>(xp_part, xdbl);
        // delta = softplus(xdbl[:, :64] @ dt_w + dt_b)
        gemm_mfma<true, true, false, false, false, false>
            <<<dim3(DINNER / 128, NTOK / 128), 256, 0, stream>>>(
            xdbl, w_dtT + (size_t)i * DINNER * DTRANK, delta, nullptr,
            dt_b + (size_t)i * DINNER, nullptr, DINNER, DTRANK, XDBLN, DTRANK, DINNER);
        // selective scan
        {
            dim3 g(DINNER / 1024, NCHUNK, NB);
            scan_phase1<<<g, 256, 0, stream>>>(
                delta, xi, xdbl, A_log + (size_t)i * DINNER * NSTATE, hf, Ssum);
            scan_phase2<<<(NB * NSTATE * DINNER) / 256, 256, 0, stream>>>(
                hf, Ssum, A_log + (size_t)i * DINNER * NSTATE);
            scan_phase3<<<g, 256, 0, stream>>>(
                delta, xi, xdbl, res,
                A_log + (size_t)i * DINNER * NSTATE, D_skip + (size_t)i * DINNER,
                hf, xi);
        }
        // x_cur = y @ out_proj + x_in   (f32 out, resid fused)
        gemm_mfma<false, false, true, false, false, false>
            <<<dim3(DMODEL / 128, NTOK / 128), 256, 0, stream>>>(
            xi, w_outT + (size_t)i * DMODEL * DINNER, x_cur, nullptr,
            nullptr, x_in, DMODEL, DINNER, DINNER, DINNER, DMODEL);
    }
    rmsnorm_kernel<false><<<NTOK, 256, 0, stream>>>(x_cur, norm_f_w, out);
}

// Round 8
// 664.622 us; speedup vs baseline: 17.5400x; 1.0335x over previous
//
#include <hip/hip_runtime.h>
#include <stdint.h>

#define DMODEL 1024
#define DINNER 2048
#define NSTATE 4
#define DTRANK 64
#define XDBLN  72
#define SEQL   4096
#define NB     2
#define NTOK   (NB * SEQL)
#define CHUNK  32
#define NCHUNK (SEQL / CHUNK)   // 128

typedef unsigned short ushort_t;
typedef __attribute__((ext_vector_type(8))) __bf16 bf16x8;
typedef __attribute__((ext_vector_type(4))) float f32x4;

__device__ __forceinline__ float bf2f(ushort_t h) {
    return __uint_as_float(((unsigned int)h) << 16);
}
__device__ __forceinline__ ushort_t f2bf(float f) {
    unsigned int u = __float_as_uint(f);
    u += 0x7fffu + ((u >> 16) & 1u);   // round-to-nearest-even
    return (ushort_t)(u >> 16);
}
__device__ __forceinline__ float lo16(unsigned int x) { return __uint_as_float(x << 16); }
__device__ __forceinline__ float hi16(unsigned int x) { return __uint_as_float(x & 0xffff0000u); }
__device__ __forceinline__ float fexp(float x) { return __expf(x); }
__device__ __forceinline__ float frcp(float x) { return __builtin_amdgcn_rcpf(x); }

// global -> LDS direct copy, 16 B per lane; lds base must be wave-uniform.
__device__ __forceinline__ void gload_lds16(const void* g, void* lds) {
    __builtin_amdgcn_global_load_lds(
        (const __attribute__((address_space(1))) unsigned int*)(uintptr_t)g,
        (__attribute__((address_space(3))) unsigned int*)(uintptr_t)lds,
        16, 0, 0);
}

// ---------------- RMSNorm: one block per token ----------------
template <bool OUT_BF16>
__global__ __launch_bounds__(256) void rmsnorm_kernel(
    const float* __restrict__ in, const float* __restrict__ w,
    void* __restrict__ outv)
{
    const int t = blockIdx.x;
    const int tid = threadIdx.x;
    const float4 v = reinterpret_cast<const float4*>(in + (size_t)t * DMODEL)[tid];
    float ss = v.x * v.x + v.y * v.y + v.z * v.z + v.w * v.w;
#pragma unroll
    for (int o = 32; o > 0; o >>= 1) ss += __shfl_xor(ss, o, 64);
    __shared__ float red[4];
    if ((tid & 63) == 0) red[tid >> 6] = ss;
    __syncthreads();
    const float total = red[0] + red[1] + red[2] + red[3];
    const float scale = rsqrtf(total * (1.0f / DMODEL) + 1e-5f);
    const float4 wv = reinterpret_cast<const float4*>(w)[tid];
    const float o0 = v.x * scale * wv.x;
    const float o1 = v.y * scale * wv.y;
    const float o2 = v.z * scale * wv.z;
    const float o3 = v.w * scale * wv.w;
    if (OUT_BF16) {
        ushort4 o;
        o.x = f2bf(o0); o.y = f2bf(o1); o.z = f2bf(o2); o.w = f2bf(o3);
        reinterpret_cast<ushort4*>((ushort_t*)outv + (size_t)t * DMODEL)[tid] = o;
    } else {
        float4 o; o.x = o0; o.y = o1; o.z = o2; o.w = o3;
        reinterpret_cast<float4*>((float*)outv + (size_t)t * DMODEL)[tid] = o;
    }
}

// ---------------- Fused weight prep: all 4 weight transposes in ONE launch ----------------
// W[K][N] f32 -> Wt[Npad][K] bf16 (pad rows zeroed).  grid.z = layer.
#define TILES_IN  ((DMODEL / 32) * ((2 * DINNER) / 32))   // 4096
#define TILES_XP  ((DINNER / 32) * (128 / 32))            // 256
#define TILES_DT  ((DTRANK / 32) * (DINNER / 32))         // 128
#define TILES_OUT ((DINNER / 32) * (DMODEL / 32))         // 2048
#define TILES_ALL (TILES_IN + TILES_XP + TILES_DT + TILES_OUT)  // 6528

__global__ __launch_bounds__(256) void prep_weights(
    const float* __restrict__ in_proj, const float* __restrict__ x_proj,
    const float* __restrict__ dt_w, const float* __restrict__ out_proj,
    ushort_t* __restrict__ w_inT, ushort_t* __restrict__ w_xpT,
    ushort_t* __restrict__ w_dtT, ushort_t* __restrict__ w_outT)
{
    const int layer = blockIdx.z;
    int tb = blockIdx.x;
    const float* src; ushort_t* dst; int K, N, Npad;
    if (tb < TILES_IN) {
        src = in_proj + (size_t)layer * DMODEL * 2 * DINNER;
        dst = w_inT + (size_t)layer * 2 * DINNER * DMODEL;
        K = DMODEL; N = 2 * DINNER; Npad = 2 * DINNER;
    } else if ((tb -= TILES_IN) < TILES_XP) {
        src = x_proj + (size_t)layer * DINNER * XDBLN;
        dst = w_xpT + (size_t)layer * 128 * DINNER;
        K = DINNER; N = XDBLN; Npad = 128;
    } else if ((tb -= TILES_XP) < TILES_DT) {
        src = dt_w + (size_t)layer * DTRANK * DINNER;
        dst = w_dtT + (size_t)layer * DINNER * DTRANK;
        K = DTRANK; N = DINNER; Npad = DINNER;
    } else {
        tb -= TILES_DT;
        src = out_proj + (size_t)layer * DINNER * DMODEL;
        dst = w_outT + (size_t)layer * DMODEL * DINNER;
        K = DINNER; N = DMODEL; Npad = DMODEL;
    }
    const int ktiles = K >> 5;
    const int k0 = (tb % ktiles) * 32, n0 = (tb / ktiles) * 32;
    __shared__ float t[32][33];
    const int tx = threadIdx.x & 31, ty = threadIdx.x >> 5;  // 32 x 8
#pragma unroll
    for (int i = 0; i < 32; i += 8) {
        const int k = k0 + ty + i, n = n0 + tx;
        t[ty + i][tx] = (n < N) ? src[(size_t)k * N + n] : 0.f;
    }
    __syncthreads();
#pragma unroll
    for (int i = 0; i < 32; i += 8) {
        const int n = n0 + ty + i, k = k0 + tx;
        if (n < Npad) dst[(size_t)n * K + k] = f2bf(t[tx][ty + i]);
    }
}

// ---------------- MFMA GEMM: C[M][N] = A(bf16,[M][lda]) @ Bt(bf16,[N][ldb])^T ----------------
// 128x128 tile, BK=32, 4 waves, global_load_lds width 16.
// 3-buffer LDS ring + counted vmcnt (never 0 mid-loop) + raw barriers.
// Block mapping: XCD k owns row-slab k (8 row-panels x all cols, col-major within
// slab) -> per-XCD L2 holds the slab's A panels (2 MB) while B streams once.
// REQUIRES gridDim.y == 64 (8 slabs x 8 row-panels). All call sites satisfy this.
template <bool OUT_BF16, bool SOFTPLUS, bool RESID, bool NGUARD, bool SPLITK, bool SPLITOUT>
__global__ __launch_bounds__(256) void gemm_mfma(
    const ushort_t* __restrict__ A, const ushort_t* __restrict__ Bt,
    void* __restrict__ Cv, void* __restrict__ Cv2,
    const float* __restrict__ bias, const float* __restrict__ resid,
    int N, int K, int lda, int ldb, int ldc)
{
    __shared__ alignas(16) ushort_t As[3][128 * 32];   // 3 x 8 KB
    __shared__ alignas(16) ushort_t Bs[3][128 * 32];   // 3 x 8 KB
    const int tid = threadIdx.x;
    const int wv = tid >> 6, ln = tid & 63;
    const int wr = wv >> 1, wc = wv & 1;
    // Slab mapping: lin%8 = XCD = row-slab; within slab, rows inner, cols outer.
    const int gx = gridDim.x;
    const int lin = blockIdx.y * gx + blockIdx.x;
    const int slab = lin & 7;
    const int pos = lin >> 3;
    const int row0 = (slab * 8 + (pos & 7)) * 128;
    const int col0 = (pos >> 3) * 128;

    if constexpr (SPLITK) {
        const int z = blockIdx.z;
        A  += (size_t)z * 512;
        Bt += (size_t)z * 512;
        Cv = (void*)((float*)Cv + (size_t)z * NTOK * 128);
    }

    const int srow = ln >> 2;          // staging row within 16-row chunk
    const int ske  = (ln & 3) * 8;     // staging k-element offset
    const int fr = ln & 15, fq = ln >> 4;
    const int nt = K >> 5;

    auto stage = [&](int buf, int t) {
        const int k0 = t << 5;
#pragma unroll
        for (int i = 0; i < 2; ++i) {
            const int chunk = wv * 2 + i;            // 0..7, wave-uniform
            const int r = chunk * 16 + srow;         // 0..127
            gload_lds16(A  + (size_t)(row0 + r) * lda + k0 + ske,
                        (char*)&As[buf][0] + chunk * 1024);
            gload_lds16(Bt + (size_t)(col0 + r) * ldb + k0 + ske,
                        (char*)&Bs[buf][0] + chunk * 1024);
        }
    };

    stage(0, 0);
    if (nt > 1) stage(1, 1);

    f32x4 acc[4][4] = {};
    int cur = 0;
    for (int t = 0; t < nt; ++t) {
        if (t + 2 < nt) {
            int nb = cur + 2; if (nb >= 3) nb -= 3;
            stage(nb, t + 2);
        }
        const int rem = nt - 1 - t;
        if (rem >= 2)      asm volatile("s_waitcnt vmcnt(8)" ::: "memory");
        else if (rem == 1) asm volatile("s_waitcnt vmcnt(4)" ::: "memory");
        else               asm volatile("s_waitcnt vmcnt(0)" ::: "memory");
        asm volatile("s_barrier" ::: "memory");   // tile t fully in LDS for all waves
        const ushort_t* as = &As[cur][0];
        const ushort_t* bs = &Bs[cur][0];
        bf16x8 af[4], bfr[4];
#pragma unroll
        for (int mi = 0; mi < 4; ++mi)
            af[mi] = *(const bf16x8*)(as + (wr * 64 + mi * 16 + fr) * 32 + fq * 8);
#pragma unroll
        for (int ni = 0; ni < 4; ++ni)
            bfr[ni] = *(const bf16x8*)(bs + (wc * 64 + ni * 16 + fr) * 32 + fq * 8);
#pragma unroll
        for (int mi = 0; mi < 4; ++mi)
#pragma unroll
            for (int ni = 0; ni < 4; ++ni)
                acc[mi][ni] = __builtin_amdgcn_mfma_f32_16x16x32_bf16(
                    af[mi], bfr[ni], acc[mi][ni], 0, 0, 0);
        asm volatile("s_barrier" ::: "memory");   // frees buf cur for stage t+3
        cur = (cur + 1 == 3) ? 0 : cur + 1;
    }

    // Output column base (SPLITOUT: route upper half to Cv2, block-uniform).
    int ccol0 = col0;
    if constexpr (SPLITOUT) {
        if (col0 >= DINNER) { Cv = Cv2; ccol0 = col0 - DINNER; }
    }

#pragma unroll
    for (int mi = 0; mi < 4; ++mi) {
#pragma unroll
        for (int ni = 0; ni < 4; ++ni) {
            const int c = ccol0 + wc * 64 + ni * 16 + fr;
            if (NGUARD && c >= N) continue;
            const float b = SOFTPLUS ? bias[c] : 0.f;
#pragma unroll
            for (int r = 0; r < 4; ++r) {
                const int rr = row0 + wr * 64 + mi * 16 + fq * 4 + r;
                float v = acc[mi][ni][r];
                if (SOFTPLUS) {
                    v += b;
                    v = fmaxf(v, 0.f) + log1pf(fexp(-fabsf(v)));
                }
                if (RESID) v += resid[(size_t)rr * ldc + c];
                if (OUT_BF16) ((ushort_t*)Cv)[(size_t)rr * ldc + c] = f2bf(v);
                else          ((float*)Cv)[(size_t)rr * ldc + c]   = v;
            }
        }
    }
}

// ---------------- x_proj split-K reduce: xdbl = f2bf(sum of 4 partials) ----------------
__global__ __launch_bounds__(128) void xp_reduce(
    const float* __restrict__ part, ushort_t* __restrict__ xdbl)
{
    const int t = blockIdx.x;          // token
    const int j = threadIdx.x;         // 0..127
    if (j >= XDBLN) return;
    const size_t o = (size_t)t * 128 + j;
    const size_t stride = (size_t)NTOK * 128;
    const float s = part[o] + part[o + stride] + part[o + 2 * stride] + part[o + 3 * stride];
    xdbl[(size_t)t * XDBLN + j] = f2bf(s);
}

// ---------------- Causal depthwise conv (K=4) + bias + SiLU, 8 channels/thread ----------------
__device__ __forceinline__ void unpack8(const uint4 v, float* a) {
    a[0] = lo16(v.x); a[1] = hi16(v.x);
    a[2] = lo16(v.y); a[3] = hi16(v.y);
    a[4] = lo16(v.z); a[5] = hi16(v.z);
    a[6] = lo16(v.w); a[7] = hi16(v.w);
}

__global__ __launch_bounds__(256) void conv_silu_kernel(
    const ushort_t* __restrict__ xr, const float* __restrict__ w,
    const float* __restrict__ bcv, ushort_t* __restrict__ xi)
{
    const int idx = blockIdx.x * 256 + threadIdx.x;  // NTOK*DINNER/8
    const int cg = idx & (DINNER / 8 - 1);
    const int t  = idx >> 8;
    const int l  = t & (SEQL - 1);
    const int c0 = cg * 8;
    const size_t base = (size_t)t * DINNER + c0;
    const uint4 zz = make_uint4(0, 0, 0, 0);
    const uint4 x3 = *reinterpret_cast<const uint4*>(xr + base);
    const uint4 x2 = (l >= 1) ? *reinterpret_cast<const uint4*>(xr + base - DINNER) : zz;
    const uint4 x1 = (l >= 2) ? *reinterpret_cast<const uint4*>(xr + base - 2 * DINNER) : zz;
    const uint4 x0 = (l >= 3) ? *reinterpret_cast<const uint4*>(xr + base - 3 * DINNER) : zz;
    float a0[8], a1[8], a2[8], a3[8];
    unpack8(x0, a0); unpack8(x1, a1); unpack8(x2, a2); unpack8(x3, a3);
    ushort_t o[8];
#pragma unroll
    for (int j = 0; j < 8; ++j) {
        const float4 wj = *reinterpret_cast<const float4*>(w + (size_t)(c0 + j) * 4);
        float s = bcv[c0 + j] + wj.x * a0[j] + wj.y * a1[j] + wj.z * a2[j] + wj.w * a3[j];
        s = s * frcp(1.0f + fexp(-s));
        o[j] = f2bf(s);
    }
    uint4 ov;
    ov.x = (unsigned int)o[0] | ((unsigned int)o[1] << 16);
    ov.y = (unsigned int)o[2] | ((unsigned int)o[3] << 16);
    ov.z = (unsigned int)o[4] | ((unsigned int)o[5] << 16);
    ov.w = (unsigned int)o[6] | ((unsigned int)o[7] << 16);
    *reinterpret_cast<uint4*>(xi + base) = ov;
}

// ---------------- Chunked selective scan (CHUNK=32, 4 d-channels per thread) ----------------
__global__ __launch_bounds__(256) void scan_phase1(
    const ushort_t* __restrict__ delta, const ushort_t* __restrict__ u_in,
    const ushort_t* __restrict__ xdbl, const float* __restrict__ A_log,
    float* __restrict__ hf,    // [B][NCHUNK][NSTATE][DINNER]
    float* __restrict__ Ssum)  // [B][NCHUNK][DINNER]
{
    const int d0 = (blockIdx.x * 256 + threadIdx.x) * 4;
    const int c = blockIdx.y;
    const int b = blockIdx.z;
    float An[4][NSTATE];
#pragma unroll
    for (int j = 0; j < 4; ++j) {
        const float4 al = *reinterpret_cast<const float4*>(A_log + (size_t)(d0 + j) * NSTATE);
        An[j][0] = -fexp(al.x); An[j][1] = -fexp(al.y);
        An[j][2] = -fexp(al.z); An[j][3] = -fexp(al.w);
    }
    float h[4][NSTATE] = {};
    float S[4] = {};
    size_t idx = ((size_t)b * SEQL + (size_t)c * CHUNK) * DINNER + d0;
    size_t idx_bc = ((size_t)b * SEQL + (size_t)c * CHUNK) * XDBLN + DTRANK;
    for (int l = 0; l < CHUNK; ++l) {
        const uint2 dv2 = *reinterpret_cast<const uint2*>(delta + idx);
        const uint2 u2  = *reinterpret_cast<const uint2*>(u_in + idx);
        const uint4 bc  = *reinterpret_cast<const uint4*>(&xdbl[idx_bc]);
        const float dv[4] = { lo16(dv2.x), hi16(dv2.x), lo16(dv2.y), hi16(dv2.y) };
        const float uu[4] = { lo16(u2.x),  hi16(u2.x),  lo16(u2.y),  hi16(u2.y)  };
        const float Bv[NSTATE] = { lo16(bc.x), hi16(bc.x), lo16(bc.y), hi16(bc.y) };
#pragma unroll
        for (int j = 0; j < 4; ++j) {
            S[j] += dv[j];
            const float dvu = dv[j] * uu[j];
#pragma unroll
            for (int n = 0; n < NSTATE; ++n)
                h[j][n] = fexp(dv[j] * An[j][n]) * h[j][n] + dvu * Bv[n];
        }
        idx += DINNER;
        idx_bc += XDBLN;
    }
    const size_t o = (((size_t)b * NCHUNK + c) * NSTATE) * DINNER + d0;
#pragma unroll
    for (int n = 0; n < NSTATE; ++n) {
        float4 v; v.x = h[0][n]; v.y = h[1][n]; v.z = h[2][n]; v.w = h[3][n];
        *reinterpret_cast<float4*>(hf + o + (size_t)n * DINNER) = v;
    }
    float4 sv; sv.x = S[0]; sv.y = S[1]; sv.z = S[2]; sv.w = S[3];
    *reinterpret_cast<float4*>(Ssum + ((size_t)b * NCHUNK + c) * DINNER + d0) = sv;
}

// Phase 2: in-place convert chunk-local finals -> incoming prefixes.
__global__ __launch_bounds__(256) void scan_phase2(
    float* __restrict__ hf, const float* __restrict__ Ssum,
    const float* __restrict__ A_log)
{
    const int gid = blockIdx.x * 256 + threadIdx.x;  // B*NSTATE*DINNER = 16384
    const int d = gid & (DINNER - 1);
    const int n = (gid >> 11) & 3;
    const int b = gid >> 13;
    const float An = -fexp(A_log[d * NSTATE + n]);
    float hin = 0.f;
    for (int c = 0; c < NCHUNK; ++c) {
        const size_t oh = (((size_t)b * NCHUNK + c) * NSTATE + n) * DINNER + d;
        const float hl = hf[oh];
        const float Sc = Ssum[((size_t)b * NCHUNK + c) * DINNER + d];
        hf[oh] = hin;
        hin = hl + fexp(An * Sc) * hin;
    }
}

// Phase 3: load h_in, run chunk recurrence, emit y fused with D-skip and *silu(res).
__global__ __launch_bounds__(256) void scan_phase3(
    const ushort_t* __restrict__ delta, const ushort_t* __restrict__ u_in,
    const ushort_t* __restrict__ xdbl, const ushort_t* __restrict__ res_in,
    const float* __restrict__ A_log, const float* __restrict__ D_skip,
    const float* __restrict__ hf, ushort_t* __restrict__ y_out)
{
    const int d0 = (blockIdx.x * 256 + threadIdx.x) * 4;
    const int c = blockIdx.y;
    const int b = blockIdx.z;
    float An[4][NSTATE];
#pragma unroll
    for (int j = 0; j < 4; ++j) {
        const float4 al = *reinterpret_cast<const float4*>(A_log + (size_t)(d0 + j) * NSTATE);
        An[j][0] = -fexp(al.x); An[j][1] = -fexp(al.y);
        An[j][2] = -fexp(al.z); An[j][3] = -fexp(al.w);
    }
    const float4 dk4 = *reinterpret_cast<const float4*>(D_skip + d0);
    const float Dk[4] = { dk4.x, dk4.y, dk4.z, dk4.w };
    float h[4][NSTATE];
    const size_t o = (((size_t)b * NCHUNK + c) * NSTATE) * DINNER + d0;
#pragma unroll
    for (int n = 0; n < NSTATE; ++n) {
        const float4 v = *reinterpret_cast<const float4*>(hf + o + (size_t)n * DINNER);
        h[0][n] = v.x; h[1][n] = v.y; h[2][n] = v.z; h[3][n] = v.w;
    }
    size_t idx = ((size_t)b * SEQL + (size_t)c * CHUNK) * DINNER + d0;
    size_t idx_bc = ((size_t)b * SEQL + (size_t)c * CHUNK) * XDBLN + DTRANK;
    for (int l = 0; l < CHUNK; ++l) {
        const uint2 dv2 = *reinterpret_cast<const uint2*>(delta + idx);
        const uint2 u2  = *reinterpret_cast<const uint2*>(u_in + idx);
        const uint2 r2  = *reinterpret_cast<const uint2*>(res_in + idx);
        const uint4 bc  = *reinterpret_cast<const uint4*>(&xdbl[idx_bc]);
        const float dv[4] = { lo16(dv2.x), hi16(dv2.x), lo16(dv2.y), hi16(dv2.y) };
        const float uu[4] = { lo16(u2.x),  hi16(u2.x),  lo16(u2.y),  hi16(u2.y)  };
        const float rr[4] = { lo16(r2.x),  hi16(r2.x),  lo16(r2.y),  hi16(r2.y)  };
        const float Bv[NSTATE] = { lo16(bc.x), hi16(bc.x), lo16(bc.y), hi16(bc.y) };
        const float Cw[NSTATE] = { lo16(bc.z), hi16(bc.z), lo16(bc.w), hi16(bc.w) };
        ushort_t yo[4];
#pragma unroll
        for (int j = 0; j < 4; ++j) {
            const float dvu = dv[j] * uu[j];
            float y = 0.f;
#pragma unroll
            for (int n = 0; n < NSTATE; ++n) {
                h[j][n] = fexp(dv[j] * An[j][n]) * h[j][n] + dvu * Bv[n];
                y += h[j][n] * Cw[n];
            }
            const float sil = rr[j] * frcp(1.0f + fexp(-rr[j]));
            yo[j] = f2bf((y + uu[j] * Dk[j]) * sil);
        }
        uint2 ov;
        ov.x = (unsigned int)yo[0] | ((unsigned int)yo[1] << 16);
        ov.y = (unsigned int)yo[2] | ((unsigned int)yo[3] << 16);
        *reinterpret_cast<uint2*>(y_out + idx) = ov;
        idx += DINNER;
        idx_bc += XDBLN;
    }
}

// ---------------- Orchestration ----------------
extern "C" void kernel_launch(void* const* d_in, const int* in_sizes, int n_in,
                              void* d_out, int out_size, void* d_ws, size_t ws_size,
                              hipStream_t stream)
{
    const float* x        = (const float*)d_in[0];
    const float* in_proj  = (const float*)d_in[1];
    const float* conv_w   = (const float*)d_in[2];
    const float* conv_b   = (const float*)d_in[3];
    const float* x_proj   = (const float*)d_in[4];
    const float* dt_w     = (const float*)d_in[5];
    const float* dt_b     = (const float*)d_in[6];
    const float* A_log    = (const float*)d_in[7];
    const float* D_skip   = (const float*)d_in[8];
    const float* out_proj = (const float*)d_in[9];
    const float* norm_w   = (const float*)d_in[10];
    const float* norm_f_w = (const float*)d_in[11];
    float* out = (float*)d_out;

    // Workspace layout: ~178.8 MB total (all chunks 16B-aligned).
    char* p = (char*)d_ws;
    float*    x_cur = (float*)p;    p += (size_t)NTOK * DMODEL * 4;    // 33.5 MB
    ushort_t* xn    = (ushort_t*)p; p += (size_t)NTOK * DMODEL * 2;    // 16.8 MB (xp partials / hf+Ssum reuse)
    ushort_t* xraw  = (ushort_t*)p; p += (size_t)NTOK * DINNER * 2;    // 33.5 MB (delta reuses)
    ushort_t* res   = (ushort_t*)p; p += (size_t)NTOK * DINNER * 2;    // 33.5 MB
    ushort_t* xi    = (ushort_t*)p; p += (size_t)NTOK * DINNER * 2;    // 33.5 MB (y in-place)
    ushort_t* xdbl  = (ushort_t*)p; p += (size_t)NTOK * XDBLN * 2;     //  1.2 MB
    ushort_t* w_inT  = (ushort_t*)p; p += (size_t)2 * 2 * DINNER * DMODEL * 2;  // 16.8 MB
    ushort_t* w_xpT  = (ushort_t*)p; p += (size_t)2 * 128 * DINNER * 2;         //  1.0 MB
    ushort_t* w_dtT  = (ushort_t*)p; p += (size_t)2 * DINNER * DTRANK * 2;      //  0.5 MB
    ushort_t* w_outT = (ushort_t*)p; p += (size_t)2 * DMODEL * DINNER * 2;      //  8.4 MB
    const size_t need = (size_t)(p - (char*)d_ws);
    if (ws_size < need) return;  // clean diagnostic failure instead of page fault
    ushort_t* delta = xraw;                 // xraw dead after conv
    float* xp_part = (float*)xn;            // 16.77 MB = 4*NTOK*128*4 exactly
    float* hf   = (float*)xn;               // 8 MB (after xp_reduce consumed partials)
    float* Ssum = hf + (size_t)NB * NCHUNK * NSTATE * DINNER;  // 2 MB

    // ---- fused weight prep (single launch, both layers) ----
    prep_weights<<<dim3(TILES_ALL, 1, 2), 256, 0, stream>>>(
        in_proj, x_proj, dt_w, out_proj, w_inT, w_xpT, w_dtT, w_outT);

    for (int i = 0; i < 2; ++i) {
        const float* x_in = (i == 0) ? x : x_cur;
        rmsnorm_kernel<true><<<NTOK, 256, 0, stream>>>(x_in, norm_w + (size_t)i * DMODEL, xn);
        // Fused in_proj: N=4096, split-output (cols<2048 -> xraw, else -> res).
        gemm_mfma<true, false, false, false, false, true>
            <<<dim3((2 * DINNER) / 128, NTOK / 128), 256, 0, stream>>>(
            xn, w_inT + (size_t)i * 2 * DINNER * DMODEL, xraw, res,
            nullptr, nullptr, 2 * DINNER, DMODEL, DMODEL, DMODEL, DINNER);
        conv_silu_kernel<<<(NTOK * DINNER / 8) / 256, 256, 0, stream>>>(
            xraw, conv_w + (size_t)i * DINNER * 4, conv_b + (size_t)i * DINNER, xi);
        // xdbl = xi @ x_proj : split-K x4 in one dispatch (grid.z), f32 partials, then reduce.
        gemm_mfma<false, false, false, false, true, false>
            <<<dim3(1, NTOK / 128, 4), 256, 0, stream>>>(
            xi, w_xpT + (size_t)i * 128 * DINNER, xp_part, nullptr,
            nullptr, nullptr, 128, 512, DINNER, DINNER, 128);
        xp_reduce<<<NTOK, 128, 0, stream>>>(xp_part, xdbl);
        // delta = softplus(xdbl[:, :64] @ dt_w + dt_b)
        gemm_mfma<true, true, false, false, false, false>
            <<<dim3(DINNER / 128, NTOK / 128), 256, 0, stream>>>(
            xdbl, w_dtT + (size_t)i * DINNER * DTRANK, delta, nullptr,
            dt_b + (size_t)i * DINNER, nullptr, DINNER, DTRANK, XDBLN, DTRANK, DINNER);
        // selective scan
        {
            dim3 g(DINNER / 1024, NCHUNK, NB);
            scan_phase1<<<g, 256, 0, stream>>>(
                delta, xi, xdbl, A_log + (size_t)i * DINNER * NSTATE, hf, Ssum);
            scan_phase2<<<(NB * NSTATE * DINNER) / 256, 256, 0, stream>>>(
                hf, Ssum, A_log + (size_t)i * DINNER * NSTATE);
            scan_phase3<<<g, 256, 0, stream>>>(
                delta, xi, xdbl, res,
                A_log + (size_t)i * DINNER * NSTATE, D_skip + (size_t)i * DINNER,
                hf, xi);
        }
        // x_cur = y @ out_proj + x_in   (f32 out, resid fused)
        gemm_mfma<false, false, true, false, false, false>
            <<<dim3(DMODEL / 128, NTOK / 128), 256, 0, stream>>>(
            xi, w_outT + (size_t)i * DMODEL * DINNER, x_cur, nullptr,
            nullptr, x_in, DMODEL, DINNER, DINNER, DINNER, DMODEL);
    }
    rmsnorm_kernel<false><<<NTOK, 256, 0, stream>>>(x_cur, norm_f_w, out);
}